// Round 5
// baseline (2425.651 us; speedup 1.0000x reference)
//
#include <hip/hip_runtime.h>
#include <cstdint>

#define N_NODES 100000
#define N_EDGES 3200000
#define N_GRAPHS 64
#define HDIM 256
#define F_IN 128

#define BUCKET_BITS 7
#define NPB 128  // nodes per bucket
#define N_BUCKETS ((N_NODES + NPB - 1) / NPB)  // 782

typedef __attribute__((ext_vector_type(8))) short bf16x8;
typedef __attribute__((ext_vector_type(4))) float f32x4;

// ---------------- bf16 helpers ----------------
__device__ __forceinline__ unsigned short f2bf(float f) {
    unsigned int b = __float_as_uint(f);
    b = (b + 0x7FFFu + ((b >> 16) & 1u)) >> 16;
    return (unsigned short)b;
}
__device__ __forceinline__ float bf2f_lo(unsigned int u) { return __uint_as_float(u << 16); }
__device__ __forceinline__ float bf2f_hi(unsigned int u) { return __uint_as_float(u & 0xFFFF0000u); }

// ---------------- utility ----------------
__global__ void zero_int(int* p, int n) {
    int i = blockIdx.x * blockDim.x + threadIdx.x;
    if (i < n) p[i] = 0;
}
__global__ void zero_f(float* p, int n) {
    int i = blockIdx.x * blockDim.x + threadIdx.x;
    if (i < n) p[i] = 0.0f;
}

// ---------------- bucketed CSR build ----------------
__global__ void bucket_hist(const int* __restrict__ dst, int* __restrict__ cnt, int nE) {
    int e = blockIdx.x * blockDim.x + threadIdx.x;
    if (e < nE) atomicAdd(&cnt[dst[e] >> BUCKET_BITS], 1);
}

// single block, 1024 threads; nb+1 <= 1024. base[nb] = total.
__global__ void scan_buckets(const int* __restrict__ cnt, int* __restrict__ base,
                             int* __restrict__ cursor, int nb) {
    __shared__ int lds[1024];
    int t = threadIdx.x;
    int v = (t < nb) ? cnt[t] : 0;
    lds[t] = v;
    __syncthreads();
    for (int off = 1; off < 1024; off <<= 1) {
        int a = (t >= off) ? lds[t - off] : 0;
        __syncthreads();
        lds[t] += a;
        __syncthreads();
    }
    int excl = lds[t] - v;
    if (t < nb) {
        base[t] = excl;
        cursor[t] = excl;
    }
    if (t == nb) base[t] = excl;  // == total edges
}

__global__ void append_edges(const int* __restrict__ src, const int* __restrict__ dst,
                             int* __restrict__ cursor, unsigned int* __restrict__ rec, int nE) {
    int e = blockIdx.x * blockDim.x + threadIdx.x;
    if (e < nE) {
        int d = dst[e];
        int b = d >> BUCKET_BITS;
        int pos = atomicAdd(&cursor[b], 1);
        rec[pos] = (unsigned int)src[e] | ((unsigned int)(d & (NPB - 1)) << 17);
    }
}

// one block per bucket: LDS histogram -> scan -> ptr/dinv -> scatter csr_src (L2-local)
__global__ __launch_bounds__(256) void bucket_csr(const unsigned int* __restrict__ rec,
                                                  const int* __restrict__ base,
                                                  int* __restrict__ ptr, float* __restrict__ dinv,
                                                  int* __restrict__ csr_src, int n) {
    __shared__ int hist[NPB];
    __shared__ int sc[NPB];
    __shared__ int cur[NPB];
    int b = blockIdx.x;
    int lo = base[b], hi = base[b + 1];
    int t = threadIdx.x;
    if (t < NPB) hist[t] = 0;
    __syncthreads();
    for (int i = lo + t; i < hi; i += 256) atomicAdd(&hist[rec[i] >> 17], 1);
    __syncthreads();
    if (t < NPB) sc[t] = hist[t];
    __syncthreads();
    for (int off = 1; off < NPB; off <<= 1) {
        int a = (t < NPB && t >= off) ? sc[t - off] : 0;
        __syncthreads();
        if (t < NPB) sc[t] += a;
        __syncthreads();
    }
    if (t < NPB) {
        int node = b * NPB + t;
        int incl = sc[t];
        int excl = incl - hist[t];
        if (node < n) {
            ptr[node] = lo + incl;
            dinv[node] = rsqrtf((float)hist[t] + 1.0f);
        }
        cur[t] = lo + excl;
    }
    __syncthreads();
    for (int i = lo + t; i < hi; i += 256) {
        unsigned int r = rec[i];
        int pos = atomicAdd(&cur[r >> 17], 1);
        csr_src[pos] = (int)(r & 0x1FFFFu);
    }
}

// ---------------- x -> bf16 pre-scaled: x_pre[n] = bf16(dinv[n] * x[n]) ----------------
__global__ void convert_x_pre(const float* __restrict__ x, const float* __restrict__ dinv,
                              unsigned short* __restrict__ xp, int n) {
    int tid = blockIdx.x * blockDim.x + threadIdx.x;  // over n*F_IN/4
    if (tid >= n * (F_IN / 4)) return;
    int node = tid / (F_IN / 4);
    float di = dinv[node];
    float4 v = ((const float4*)x)[tid];
    ushort4 o;
    o.x = f2bf(v.x * di); o.y = f2bf(v.y * di); o.z = f2bf(v.z * di); o.w = f2bf(v.w * di);
    ((ushort4*)xp)[tid] = o;
}

// ---------------- pack W[K][256] fp32 -> hi/lo bf16 in MFMA B-fragment order ----------------
__global__ void pack_w(const float* __restrict__ W, unsigned short* __restrict__ hi,
                       unsigned short* __restrict__ lo, int K) {
    int idx = blockIdx.x * blockDim.x + threadIdx.x;
    if (idx >= K * HDIM) return;
    int k = idx >> 8, c = idx & 255;
    float w = W[idx];
    unsigned short h = f2bf(w);
    float hf = __uint_as_float((unsigned int)h << 16);
    unsigned short l = f2bf(w - hf);
    int pos = ((k >> 5) * 16 + (c >> 4)) * 512 + ((((k >> 3) & 3) * 16) + (c & 15)) * 8 + (k & 7);
    hi[pos] = h;
    lo[pos] = l;
}

// ---------------- aggregation (bf16 in, bf16 out) ----------------
__global__ void csr_agg128_bf16(const unsigned short* __restrict__ h, const int* __restrict__ ptr,
                                const int* __restrict__ csr, const float* __restrict__ dinv,
                                unsigned short* __restrict__ out, int n) {
    int wave = threadIdx.x >> 6, lane = threadIdx.x & 63;
    int node = blockIdx.x * 4 + wave;
    if (node >= n) return;
    int begin = node ? ptr[node - 1] : 0;
    int end = ptr[node];
    unsigned int u = *(const unsigned int*)(h + (size_t)node * 128 + lane * 2);
    float a0 = bf2f_lo(u), a1 = bf2f_hi(u);
    int i = begin;
    for (; i + 1 < end; i += 2) {
        int s0 = csr[i], s1 = csr[i + 1];
        unsigned int u0 = *(const unsigned int*)(h + (size_t)s0 * 128 + lane * 2);
        unsigned int u1 = *(const unsigned int*)(h + (size_t)s1 * 128 + lane * 2);
        a0 += bf2f_lo(u0); a1 += bf2f_hi(u0);
        a0 += bf2f_lo(u1); a1 += bf2f_hi(u1);
    }
    if (i < end) {
        int s = csr[i];
        unsigned int u0 = *(const unsigned int*)(h + (size_t)s * 128 + lane * 2);
        a0 += bf2f_lo(u0); a1 += bf2f_hi(u0);
    }
    float dn = dinv[node];
    unsigned int o = (unsigned int)f2bf(a0 * dn) | ((unsigned int)f2bf(a1 * dn) << 16);
    *(unsigned int*)(out + (size_t)node * 128 + lane * 2) = o;
}

__global__ void csr_agg256_bf16(const unsigned short* __restrict__ h, const int* __restrict__ ptr,
                                const int* __restrict__ csr, const float* __restrict__ dinv,
                                unsigned short* __restrict__ out, int n) {
    int wave = threadIdx.x >> 6, lane = threadIdx.x & 63;
    int node = blockIdx.x * 4 + wave;
    if (node >= n) return;
    int begin = node ? ptr[node - 1] : 0;
    int end = ptr[node];
    uint2 u = *(const uint2*)(h + (size_t)node * 256 + lane * 4);
    float a0 = bf2f_lo(u.x), a1 = bf2f_hi(u.x), a2 = bf2f_lo(u.y), a3 = bf2f_hi(u.y);
    int i = begin;
    for (; i + 1 < end; i += 2) {
        int s0 = csr[i], s1 = csr[i + 1];
        uint2 u0 = *(const uint2*)(h + (size_t)s0 * 256 + lane * 4);
        uint2 u1 = *(const uint2*)(h + (size_t)s1 * 256 + lane * 4);
        a0 += bf2f_lo(u0.x); a1 += bf2f_hi(u0.x); a2 += bf2f_lo(u0.y); a3 += bf2f_hi(u0.y);
        a0 += bf2f_lo(u1.x); a1 += bf2f_hi(u1.x); a2 += bf2f_lo(u1.y); a3 += bf2f_hi(u1.y);
    }
    if (i < end) {
        int s = csr[i];
        uint2 u0 = *(const uint2*)(h + (size_t)s * 256 + lane * 4);
        a0 += bf2f_lo(u0.x); a1 += bf2f_hi(u0.x); a2 += bf2f_lo(u0.y); a3 += bf2f_hi(u0.y);
    }
    float dn = dinv[node];
    uint2 o;
    o.x = (unsigned int)f2bf(a0 * dn) | ((unsigned int)f2bf(a1 * dn) << 16);
    o.y = (unsigned int)f2bf(a2 * dn) | ((unsigned int)f2bf(a3 * dn) << 16);
    *(uint2*)(out + (size_t)node * 256 + lane * 4) = o;
}

// ---------------- MFMA GEMM: out[n,256] = act(A[n,K] @ (Whi+Wlo) + b) ----------------
template <int K, bool PRESCALE>
__global__ __launch_bounds__(256) void gemm_mfma(
    const unsigned short* __restrict__ A, const unsigned short* __restrict__ Whi,
    const unsigned short* __restrict__ Wlo, const float* __restrict__ bias,
    const float* __restrict__ dinv, void* __restrict__ outp, int n) {
    int wave = threadIdx.x >> 6, lane = threadIdx.x & 63;
    int quad = lane >> 4, l16 = lane & 15;
    int rowbase = blockIdx.x * 128 + wave * 32;

    f32x4 acc[2][16];
#pragma unroll
    for (int s = 0; s < 2; s++)
#pragma unroll
        for (int ct = 0; ct < 16; ct++) acc[s][ct] = (f32x4){0.f, 0.f, 0.f, 0.f};

    int r0 = rowbase + l16;
    int r1 = rowbase + 16 + l16;
    int rc0 = r0 < n ? r0 : n - 1;
    int rc1 = r1 < n ? r1 : n - 1;

    for (int kt = 0; kt < K / 32; kt++) {
        bf16x8 a0 = *(const bf16x8*)(A + (size_t)rc0 * K + kt * 32 + quad * 8);
        bf16x8 a1 = *(const bf16x8*)(A + (size_t)rc1 * K + kt * 32 + quad * 8);
        const unsigned short* wh = Whi + (size_t)kt * 16 * 512;
        const unsigned short* wl = Wlo + (size_t)kt * 16 * 512;
#pragma unroll
        for (int ct = 0; ct < 16; ct++) {
            bf16x8 bh = *(const bf16x8*)(wh + ct * 512 + lane * 8);
            bf16x8 bl = *(const bf16x8*)(wl + ct * 512 + lane * 8);
            acc[0][ct] = __builtin_amdgcn_mfma_f32_16x16x32_bf16(a0, bh, acc[0][ct], 0, 0, 0);
            acc[0][ct] = __builtin_amdgcn_mfma_f32_16x16x32_bf16(a0, bl, acc[0][ct], 0, 0, 0);
            acc[1][ct] = __builtin_amdgcn_mfma_f32_16x16x32_bf16(a1, bh, acc[1][ct], 0, 0, 0);
            acc[1][ct] = __builtin_amdgcn_mfma_f32_16x16x32_bf16(a1, bl, acc[1][ct], 0, 0, 0);
        }
    }

#pragma unroll
    for (int s = 0; s < 2; s++) {
#pragma unroll
        for (int ct = 0; ct < 16; ct++) {
            int col = ct * 16 + l16;
            float b = bias[col];
#pragma unroll
            for (int r = 0; r < 4; r++) {
                int row = rowbase + s * 16 + quad * 4 + r;
                if (row < n) {
                    float v = acc[s][ct][r] + b;
                    v = v > 0.0f ? v : 0.0f;
                    if (PRESCALE) {
                        ((unsigned short*)outp)[(size_t)row * HDIM + col] = f2bf(v * dinv[row]);
                    } else {
                        ((float*)outp)[(size_t)row * HDIM + col] = v;
                    }
                }
            }
        }
    }
}

// ---------------- pooling (batch sorted -> run-length) ----------------
__global__ void pool_sum_runs(const float* __restrict__ h, const int* __restrict__ batch,
                              float* __restrict__ pool, float* __restrict__ cnt, int n) {
    constexpr int ROWS = 128;
    int f = threadIdx.x;
    int r0 = blockIdx.x * ROWS;
    int rend = r0 + ROWS;
    if (rend > n) rend = n;
    float acc = 0.0f;
    int cur = batch[r0];
    int runlen = 0;
    for (int r = r0; r < rend; r++) {
        int g = batch[r];
        if (g != cur) {
            atomicAdd(&pool[cur * HDIM + f], acc);
            if (f == 0) atomicAdd(&cnt[cur], (float)runlen);
            acc = 0.0f; runlen = 0; cur = g;
        }
        acc += h[(size_t)r * HDIM + f];
        runlen++;
    }
    atomicAdd(&pool[cur * HDIM + f], acc);
    if (f == 0) atomicAdd(&cnt[cur], (float)runlen);
}

__global__ void final_head(const float* __restrict__ pool, const float* __restrict__ cnt,
                           const float* __restrict__ fcw, const float* __restrict__ fcb,
                           float* __restrict__ out) {
    int g = threadIdx.x;
    if (g < N_GRAPHS) {
        float c = cnt[g];
        c = c > 1.0f ? c : 1.0f;
        float inv = 1.0f / c;
        float l0 = fcb[0], l1 = fcb[1];
        for (int f = 0; f < HDIM; f++) {
            float p = pool[g * HDIM + f] * inv;
            l0 += p * fcw[f * 2 + 0];
            l1 += p * fcw[f * 2 + 1];
        }
        float m = fmaxf(l0, l1);
        float lse = m + logf(expf(l0 - m) + expf(l1 - m));
        out[g * 2 + 0] = l0 - lse;
        out[g * 2 + 1] = l1 - lse;
    }
}

extern "C" void kernel_launch(void* const* d_in, const int* in_sizes, int n_in,
                              void* d_out, int out_size, void* d_ws, size_t ws_size,
                              hipStream_t stream) {
    const float* x = (const float*)d_in[0];
    const int* ei = (const int*)d_in[1];
    const int* batch = (const int*)d_in[2];
    const float* W1 = (const float*)d_in[3];
    const float* b1 = (const float*)d_in[4];
    const float* W2 = (const float*)d_in[5];
    const float* b2 = (const float*)d_in[6];
    const float* fcw = (const float*)d_in[7];
    const float* fcb = (const float*)d_in[8];
    float* out = (float*)d_out;

    const int* src = ei;
    const int* dst = ei + N_EDGES;

    // ---- workspace layout (bytes) ----
    char* ws = (char*)d_ws;
    float* dinv = (float*)ws;            ws += 4 * ((N_NODES + 255) & ~255);
    int* ptr = (int*)ws;                 ws += 4 * ((N_NODES + 255) & ~255);
    int* csr_src = (int*)ws;             ws += 4 * (size_t)N_EDGES;
    int* bcnt = (int*)ws;                ws += 4 * 1024;
    int* bbase = (int*)ws;               ws += 4 * 1024;
    int* bcur = (int*)ws;                ws += 4 * 1024;
    unsigned short* W1hi = (unsigned short*)ws; ws += 2 * F_IN * HDIM;
    unsigned short* W1lo = (unsigned short*)ws; ws += 2 * F_IN * HDIM;
    unsigned short* W2hi = (unsigned short*)ws; ws += 2 * HDIM * HDIM;
    unsigned short* W2lo = (unsigned short*)ws; ws += 2 * HDIM * HDIM;
    float* pool = (float*)ws;            ws += 4 * N_GRAPHS * HDIM;
    float* cnt = (float*)ws;             ws += 4 * ((N_GRAPHS + 63) & ~63);
    // R0 region: x_pre | A1 | h1_pre (bf16), later reused as h2 (fp32, N*256)
    char* R0 = ws;                       ws += 4 * (size_t)N_NODES * HDIM;
    unsigned short* x_pre = (unsigned short*)R0;                             // N*128 bf16
    unsigned short* A1 = (unsigned short*)(R0 + 2 * (size_t)N_NODES * F_IN); // N*128 bf16
    unsigned short* h1_pre = (unsigned short*)(R0 + 4 * (size_t)N_NODES * F_IN); // N*256 bf16
    float* h2 = (float*)R0;                                                  // N*256 fp32
    unsigned short* A2 = (unsigned short*)ws;  // N*256 bf16 (layer 2 only)
    // records overlay A2 (dead until layer 2): N_EDGES*4 = 12.8MB <= 51.2MB
    unsigned int* records = (unsigned int*)A2;

    // ---- bucketed CSR build + dinv ----
    zero_int<<<(N_BUCKETS + 255) / 256, 256, 0, stream>>>(bcnt, N_BUCKETS);
    bucket_hist<<<(N_EDGES + 255) / 256, 256, 0, stream>>>(dst, bcnt, N_EDGES);
    scan_buckets<<<1, 1024, 0, stream>>>(bcnt, bbase, bcur, N_BUCKETS);
    append_edges<<<(N_EDGES + 255) / 256, 256, 0, stream>>>(src, dst, bcur, records, N_EDGES);
    bucket_csr<<<N_BUCKETS, 256, 0, stream>>>(records, bbase, ptr, dinv, csr_src, N_NODES);

    // ---- conversions / weight packing ----
    convert_x_pre<<<(N_NODES * (F_IN / 4) + 255) / 256, 256, 0, stream>>>(x, dinv, x_pre, N_NODES);
    pack_w<<<(F_IN * HDIM + 255) / 256, 256, 0, stream>>>(W1, W1hi, W1lo, F_IN);
    pack_w<<<(HDIM * HDIM + 255) / 256, 256, 0, stream>>>(W2, W2hi, W2lo, HDIM);

    // ---- layer 1 ----
    csr_agg128_bf16<<<(N_NODES + 3) / 4, 256, 0, stream>>>(x_pre, ptr, csr_src, dinv, A1, N_NODES);
    gemm_mfma<F_IN, true><<<(N_NODES + 127) / 128, 256, 0, stream>>>(A1, W1hi, W1lo, b1, dinv,
                                                                     h1_pre, N_NODES);
    // ---- layer 2 ----
    csr_agg256_bf16<<<(N_NODES + 3) / 4, 256, 0, stream>>>(h1_pre, ptr, csr_src, dinv, A2, N_NODES);
    gemm_mfma<HDIM, false><<<(N_NODES + 127) / 128, 256, 0, stream>>>(A2, W2hi, W2lo, b2, dinv,
                                                                      h2, N_NODES);

    // ---- pool + head ----
    zero_f<<<(N_GRAPHS * HDIM + N_GRAPHS + 255) / 256, 256, 0, stream>>>(
        pool, N_GRAPHS * HDIM + N_GRAPHS);
    pool_sum_runs<<<(N_NODES + 127) / 128, 256, 0, stream>>>(h2, batch, pool, cnt, N_NODES);
    final_head<<<1, 64, 0, stream>>>(pool, cnt, fcw, fcb, out);
}

// Round 6
// 1059.849 us; speedup vs baseline: 2.2887x; 2.2887x over previous
//
#include <hip/hip_runtime.h>
#include <cstdint>

#define N_NODES 100000
#define N_EDGES 3200000
#define N_GRAPHS 64
#define HDIM 256
#define F_IN 128

#define BUCKET_BITS 7
#define NPB 128                                 // nodes per bucket
#define N_BUCKETS ((N_NODES + NPB - 1) / NPB)   // 782
#define CHUNK 8192
#define NCHUNK ((N_EDGES + CHUNK - 1) / CHUNK)  // 391

typedef __attribute__((ext_vector_type(8))) short bf16x8;
typedef __attribute__((ext_vector_type(4))) float f32x4;

// ---------------- bf16 helpers ----------------
__device__ __forceinline__ unsigned short f2bf(float f) {
    unsigned int b = __float_as_uint(f);
    b = (b + 0x7FFFu + ((b >> 16) & 1u)) >> 16;
    return (unsigned short)b;
}
__device__ __forceinline__ float bf2f_lo(unsigned int u) { return __uint_as_float(u << 16); }
__device__ __forceinline__ float bf2f_hi(unsigned int u) { return __uint_as_float(u & 0xFFFF0000u); }

// ---------------- utility ----------------
__global__ void zero_f(float* p, int n) {
    int i = blockIdx.x * blockDim.x + threadIdx.x;
    if (i < n) p[i] = 0.0f;
}

// ---------------- atomic-free multisplit CSR build ----------------
// pass 1: per-chunk bucket histogram (LDS only), counts[blk][bucket]
__global__ __launch_bounds__(256) void block_count(const int* __restrict__ dst,
                                                   int* __restrict__ counts, int nE) {
    __shared__ int hist[N_BUCKETS];
    int blk = blockIdx.x, t = threadIdx.x;
    for (int i = t; i < N_BUCKETS; i += 256) hist[i] = 0;
    __syncthreads();
    int lo = blk * CHUNK;
    int hi = lo + CHUNK < nE ? lo + CHUNK : nE;
    for (int i = lo + t; i < hi; i += 256) atomicAdd(&hist[dst[i] >> BUCKET_BITS], 1);
    __syncthreads();
    for (int i = t; i < N_BUCKETS; i += 256) counts[blk * N_BUCKETS + i] = hist[i];
}

// per-bucket totals: tot[b] = sum over chunks
__global__ __launch_bounds__(256) void bucket_totals(const int* __restrict__ counts,
                                                     int* __restrict__ tot) {
    __shared__ int red[256];
    int b = blockIdx.x, t = threadIdx.x;
    int s = 0;
    for (int blk = t; blk < NCHUNK; blk += 256) s += counts[blk * N_BUCKETS + b];
    red[t] = s;
    __syncthreads();
    for (int o = 128; o > 0; o >>= 1) {
        if (t < o) red[t] += red[t + o];
        __syncthreads();
    }
    if (t == 0) tot[b] = red[0];
}

// single block scan over bucket totals -> base[b], base[nb] = total
__global__ __launch_bounds__(1024) void scan_buckets(const int* __restrict__ tot,
                                                     int* __restrict__ base, int nb) {
    __shared__ int lds[1024];
    int t = threadIdx.x;
    int v = (t < nb) ? tot[t] : 0;
    lds[t] = v;
    __syncthreads();
    for (int off = 1; off < 1024; off <<= 1) {
        int a = (t >= off) ? lds[t - off] : 0;
        __syncthreads();
        lds[t] += a;
        __syncthreads();
    }
    int excl = lds[t] - v;
    if (t < nb) base[t] = excl;
    if (t == nb) base[t] = excl;
}

// per-bucket column scan over chunks: offs[blk][b] = base[b] + prefix(counts[.][b])
__global__ __launch_bounds__(512) void column_scan(const int* __restrict__ counts,
                                                   const int* __restrict__ base,
                                                   int* __restrict__ offs) {
    __shared__ int lds[512];
    int b = blockIdx.x, t = threadIdx.x;
    int v = (t < NCHUNK) ? counts[t * N_BUCKETS + b] : 0;
    lds[t] = v;
    __syncthreads();
    for (int off = 1; off < 512; off <<= 1) {
        int a = (t >= off) ? lds[t - off] : 0;
        __syncthreads();
        lds[t] += a;
        __syncthreads();
    }
    if (t < NCHUNK) offs[t * N_BUCKETS + b] = base[b] + lds[t] - v;
}

// pass 2: scatter records into bucket runs; LDS cursors only
__global__ __launch_bounds__(256) void block_scatter(const int* __restrict__ src,
                                                     const int* __restrict__ dst,
                                                     const int* __restrict__ offs,
                                                     unsigned int* __restrict__ rec, int nE) {
    __shared__ int cur[N_BUCKETS];
    int blk = blockIdx.x, t = threadIdx.x;
    for (int i = t; i < N_BUCKETS; i += 256) cur[i] = offs[blk * N_BUCKETS + i];
    __syncthreads();
    int lo = blk * CHUNK;
    int hi = lo + CHUNK < nE ? lo + CHUNK : nE;
    for (int i = lo + t; i < hi; i += 256) {
        int d = dst[i];
        int b = d >> BUCKET_BITS;
        int pos = atomicAdd(&cur[b], 1);  // LDS atomic
        rec[pos] = (unsigned int)src[i] | ((unsigned int)(d & (NPB - 1)) << 17);
    }
}

// one block per bucket: LDS histogram -> scan -> ptr/dinv -> scatter csr_src (L2-local)
__global__ __launch_bounds__(512) void bucket_csr(const unsigned int* __restrict__ rec,
                                                  const int* __restrict__ base,
                                                  int* __restrict__ ptr, float* __restrict__ dinv,
                                                  int* __restrict__ csr_src, int n) {
    __shared__ int hist[NPB];
    __shared__ int sc[NPB];
    __shared__ int cur[NPB];
    int b = blockIdx.x;
    int lo = base[b], hi = base[b + 1];
    int t = threadIdx.x;
    if (t < NPB) hist[t] = 0;
    __syncthreads();
    for (int i = lo + t; i < hi; i += 512) atomicAdd(&hist[rec[i] >> 17], 1);
    __syncthreads();
    if (t < NPB) sc[t] = hist[t];
    __syncthreads();
    for (int off = 1; off < NPB; off <<= 1) {
        int a = (t < NPB && t >= off) ? sc[t - off] : 0;
        __syncthreads();
        if (t < NPB) sc[t] += a;
        __syncthreads();
    }
    if (t < NPB) {
        int node = b * NPB + t;
        int incl = sc[t];
        int excl = incl - hist[t];
        if (node < n) {
            ptr[node] = lo + incl;
            dinv[node] = rsqrtf((float)hist[t] + 1.0f);
        }
        cur[t] = lo + excl;
    }
    __syncthreads();
    for (int i = lo + t; i < hi; i += 512) {
        unsigned int r = rec[i];
        int pos = atomicAdd(&cur[r >> 17], 1);
        csr_src[pos] = (int)(r & 0x1FFFFu);
    }
}

// ---------------- x -> bf16 pre-scaled: x_pre[n] = bf16(dinv[n] * x[n]) ----------------
__global__ void convert_x_pre(const float* __restrict__ x, const float* __restrict__ dinv,
                              unsigned short* __restrict__ xp, int n) {
    int tid = blockIdx.x * blockDim.x + threadIdx.x;  // over n*F_IN/4
    if (tid >= n * (F_IN / 4)) return;
    int node = tid / (F_IN / 4);
    float di = dinv[node];
    float4 v = ((const float4*)x)[tid];
    ushort4 o;
    o.x = f2bf(v.x * di); o.y = f2bf(v.y * di); o.z = f2bf(v.z * di); o.w = f2bf(v.w * di);
    ((ushort4*)xp)[tid] = o;
}

// ---------------- pack W[K][256] fp32 -> hi/lo bf16 in MFMA B-fragment order ----------------
__global__ void pack_w(const float* __restrict__ W, unsigned short* __restrict__ hi,
                       unsigned short* __restrict__ lo, int K) {
    int idx = blockIdx.x * blockDim.x + threadIdx.x;
    if (idx >= K * HDIM) return;
    int k = idx >> 8, c = idx & 255;
    float w = W[idx];
    unsigned short h = f2bf(w);
    float hf = __uint_as_float((unsigned int)h << 16);
    unsigned short l = f2bf(w - hf);
    int pos = ((k >> 5) * 16 + (c >> 4)) * 512 + ((((k >> 3) & 3) * 16) + (c & 15)) * 8 + (k & 7);
    hi[pos] = h;
    lo[pos] = l;
}

// ---------------- aggregation (bf16 in, bf16 out) ----------------
__global__ void csr_agg128_bf16(const unsigned short* __restrict__ h, const int* __restrict__ ptr,
                                const int* __restrict__ csr, const float* __restrict__ dinv,
                                unsigned short* __restrict__ out, int n) {
    int wave = threadIdx.x >> 6, lane = threadIdx.x & 63;
    int node = blockIdx.x * 4 + wave;
    if (node >= n) return;
    int begin = node ? ptr[node - 1] : 0;
    int end = ptr[node];
    unsigned int u = *(const unsigned int*)(h + (size_t)node * 128 + lane * 2);
    float a0 = bf2f_lo(u), a1 = bf2f_hi(u);
    int i = begin;
    for (; i + 1 < end; i += 2) {
        int s0 = csr[i], s1 = csr[i + 1];
        unsigned int u0 = *(const unsigned int*)(h + (size_t)s0 * 128 + lane * 2);
        unsigned int u1 = *(const unsigned int*)(h + (size_t)s1 * 128 + lane * 2);
        a0 += bf2f_lo(u0); a1 += bf2f_hi(u0);
        a0 += bf2f_lo(u1); a1 += bf2f_hi(u1);
    }
    if (i < end) {
        int s = csr[i];
        unsigned int u0 = *(const unsigned int*)(h + (size_t)s * 128 + lane * 2);
        a0 += bf2f_lo(u0); a1 += bf2f_hi(u0);
    }
    float dn = dinv[node];
    unsigned int o = (unsigned int)f2bf(a0 * dn) | ((unsigned int)f2bf(a1 * dn) << 16);
    *(unsigned int*)(out + (size_t)node * 128 + lane * 2) = o;
}

__global__ void csr_agg256_bf16(const unsigned short* __restrict__ h, const int* __restrict__ ptr,
                                const int* __restrict__ csr, const float* __restrict__ dinv,
                                unsigned short* __restrict__ out, int n) {
    int wave = threadIdx.x >> 6, lane = threadIdx.x & 63;
    int node = blockIdx.x * 4 + wave;
    if (node >= n) return;
    int begin = node ? ptr[node - 1] : 0;
    int end = ptr[node];
    uint2 u = *(const uint2*)(h + (size_t)node * 256 + lane * 4);
    float a0 = bf2f_lo(u.x), a1 = bf2f_hi(u.x), a2 = bf2f_lo(u.y), a3 = bf2f_hi(u.y);
    int i = begin;
    for (; i + 1 < end; i += 2) {
        int s0 = csr[i], s1 = csr[i + 1];
        uint2 u0 = *(const uint2*)(h + (size_t)s0 * 256 + lane * 4);
        uint2 u1 = *(const uint2*)(h + (size_t)s1 * 256 + lane * 4);
        a0 += bf2f_lo(u0.x); a1 += bf2f_hi(u0.x); a2 += bf2f_lo(u0.y); a3 += bf2f_hi(u0.y);
        a0 += bf2f_lo(u1.x); a1 += bf2f_hi(u1.x); a2 += bf2f_lo(u1.y); a3 += bf2f_hi(u1.y);
    }
    if (i < end) {
        int s = csr[i];
        uint2 u0 = *(const uint2*)(h + (size_t)s * 256 + lane * 4);
        a0 += bf2f_lo(u0.x); a1 += bf2f_hi(u0.x); a2 += bf2f_lo(u0.y); a3 += bf2f_hi(u0.y);
    }
    float dn = dinv[node];
    uint2 o;
    o.x = (unsigned int)f2bf(a0 * dn) | ((unsigned int)f2bf(a1 * dn) << 16);
    o.y = (unsigned int)f2bf(a2 * dn) | ((unsigned int)f2bf(a3 * dn) << 16);
    *(uint2*)(out + (size_t)node * 256 + lane * 4) = o;
}

// ---------------- MFMA GEMM: out[n,256] = act(A[n,K] @ (Whi+Wlo) + b) ----------------
template <int K, bool PRESCALE>
__global__ __launch_bounds__(256) void gemm_mfma(
    const unsigned short* __restrict__ A, const unsigned short* __restrict__ Whi,
    const unsigned short* __restrict__ Wlo, const float* __restrict__ bias,
    const float* __restrict__ dinv, void* __restrict__ outp, int n) {
    int wave = threadIdx.x >> 6, lane = threadIdx.x & 63;
    int quad = lane >> 4, l16 = lane & 15;
    int rowbase = blockIdx.x * 128 + wave * 32;

    f32x4 acc[2][16];
#pragma unroll
    for (int s = 0; s < 2; s++)
#pragma unroll
        for (int ct = 0; ct < 16; ct++) acc[s][ct] = (f32x4){0.f, 0.f, 0.f, 0.f};

    int r0 = rowbase + l16;
    int r1 = rowbase + 16 + l16;
    int rc0 = r0 < n ? r0 : n - 1;
    int rc1 = r1 < n ? r1 : n - 1;

    for (int kt = 0; kt < K / 32; kt++) {
        bf16x8 a0 = *(const bf16x8*)(A + (size_t)rc0 * K + kt * 32 + quad * 8);
        bf16x8 a1 = *(const bf16x8*)(A + (size_t)rc1 * K + kt * 32 + quad * 8);
        const unsigned short* wh = Whi + (size_t)kt * 16 * 512;
        const unsigned short* wl = Wlo + (size_t)kt * 16 * 512;
#pragma unroll
        for (int ct = 0; ct < 16; ct++) {
            bf16x8 bh = *(const bf16x8*)(wh + ct * 512 + lane * 8);
            bf16x8 bl = *(const bf16x8*)(wl + ct * 512 + lane * 8);
            acc[0][ct] = __builtin_amdgcn_mfma_f32_16x16x32_bf16(a0, bh, acc[0][ct], 0, 0, 0);
            acc[0][ct] = __builtin_amdgcn_mfma_f32_16x16x32_bf16(a0, bl, acc[0][ct], 0, 0, 0);
            acc[1][ct] = __builtin_amdgcn_mfma_f32_16x16x32_bf16(a1, bh, acc[1][ct], 0, 0, 0);
            acc[1][ct] = __builtin_amdgcn_mfma_f32_16x16x32_bf16(a1, bl, acc[1][ct], 0, 0, 0);
        }
    }

#pragma unroll
    for (int s = 0; s < 2; s++) {
#pragma unroll
        for (int ct = 0; ct < 16; ct++) {
            int col = ct * 16 + l16;
            float b = bias[col];
#pragma unroll
            for (int r = 0; r < 4; r++) {
                int row = rowbase + s * 16 + quad * 4 + r;
                if (row < n) {
                    float v = acc[s][ct][r] + b;
                    v = v > 0.0f ? v : 0.0f;
                    if (PRESCALE) {
                        ((unsigned short*)outp)[(size_t)row * HDIM + col] = f2bf(v * dinv[row]);
                    } else {
                        ((float*)outp)[(size_t)row * HDIM + col] = v;
                    }
                }
            }
        }
    }
}

// ---------------- pooling (batch sorted -> run-length) ----------------
__global__ void pool_sum_runs(const float* __restrict__ h, const int* __restrict__ batch,
                              float* __restrict__ pool, float* __restrict__ cnt, int n) {
    constexpr int ROWS = 128;
    int f = threadIdx.x;
    int r0 = blockIdx.x * ROWS;
    int rend = r0 + ROWS;
    if (rend > n) rend = n;
    float acc = 0.0f;
    int cur = batch[r0];
    int runlen = 0;
    for (int r = r0; r < rend; r++) {
        int g = batch[r];
        if (g != cur) {
            atomicAdd(&pool[cur * HDIM + f], acc);
            if (f == 0) atomicAdd(&cnt[cur], (float)runlen);
            acc = 0.0f; runlen = 0; cur = g;
        }
        acc += h[(size_t)r * HDIM + f];
        runlen++;
    }
    atomicAdd(&pool[cur * HDIM + f], acc);
    if (f == 0) atomicAdd(&cnt[cur], (float)runlen);
}

__global__ void final_head(const float* __restrict__ pool, const float* __restrict__ cnt,
                           const float* __restrict__ fcw, const float* __restrict__ fcb,
                           float* __restrict__ out) {
    int g = threadIdx.x;
    if (g < N_GRAPHS) {
        float c = cnt[g];
        c = c > 1.0f ? c : 1.0f;
        float inv = 1.0f / c;
        float l0 = fcb[0], l1 = fcb[1];
        for (int f = 0; f < HDIM; f++) {
            float p = pool[g * HDIM + f] * inv;
            l0 += p * fcw[f * 2 + 0];
            l1 += p * fcw[f * 2 + 1];
        }
        float m = fmaxf(l0, l1);
        float lse = m + logf(expf(l0 - m) + expf(l1 - m));
        out[g * 2 + 0] = l0 - lse;
        out[g * 2 + 1] = l1 - lse;
    }
}

extern "C" void kernel_launch(void* const* d_in, const int* in_sizes, int n_in,
                              void* d_out, int out_size, void* d_ws, size_t ws_size,
                              hipStream_t stream) {
    const float* x = (const float*)d_in[0];
    const int* ei = (const int*)d_in[1];
    const int* batch = (const int*)d_in[2];
    const float* W1 = (const float*)d_in[3];
    const float* b1 = (const float*)d_in[4];
    const float* W2 = (const float*)d_in[5];
    const float* b2 = (const float*)d_in[6];
    const float* fcw = (const float*)d_in[7];
    const float* fcb = (const float*)d_in[8];
    float* out = (float*)d_out;

    const int* src = ei;
    const int* dst = ei + N_EDGES;

    // ---- workspace layout (bytes) ----
    char* ws = (char*)d_ws;
    float* dinv = (float*)ws;            ws += 4 * ((N_NODES + 255) & ~255);
    int* ptr = (int*)ws;                 ws += 4 * ((N_NODES + 255) & ~255);
    int* csr_src = (int*)ws;             ws += 4 * (size_t)N_EDGES;
    int* counts = (int*)ws;              ws += 4 * (size_t)NCHUNK * N_BUCKETS;
    int* offs = (int*)ws;                ws += 4 * (size_t)NCHUNK * N_BUCKETS;
    int* tot = (int*)ws;                 ws += 4 * 1024;
    int* bbase = (int*)ws;               ws += 4 * 1024;
    unsigned short* W1hi = (unsigned short*)ws; ws += 2 * F_IN * HDIM;
    unsigned short* W1lo = (unsigned short*)ws; ws += 2 * F_IN * HDIM;
    unsigned short* W2hi = (unsigned short*)ws; ws += 2 * HDIM * HDIM;
    unsigned short* W2lo = (unsigned short*)ws; ws += 2 * HDIM * HDIM;
    float* pool = (float*)ws;            ws += 4 * N_GRAPHS * HDIM;
    float* cnt = (float*)ws;             ws += 4 * ((N_GRAPHS + 63) & ~63);
    // R0 region: x_pre | A1 | h1_pre (bf16), later reused as h2 (fp32, N*256)
    char* R0 = ws;                       ws += 4 * (size_t)N_NODES * HDIM;
    unsigned short* x_pre = (unsigned short*)R0;                             // N*128 bf16
    unsigned short* A1 = (unsigned short*)(R0 + 2 * (size_t)N_NODES * F_IN); // N*128 bf16
    unsigned short* h1_pre = (unsigned short*)(R0 + 4 * (size_t)N_NODES * F_IN); // N*256 bf16
    float* h2 = (float*)R0;                                                  // N*256 fp32
    unsigned short* A2 = (unsigned short*)ws;  // N*256 bf16 (layer 2 only)
    // records overlay A2 (dead until layer 2): N_EDGES*4 = 12.8MB <= 51.2MB
    unsigned int* records = (unsigned int*)A2;

    // ---- atomic-free bucketed CSR build + dinv ----
    block_count<<<NCHUNK, 256, 0, stream>>>(dst, counts, N_EDGES);
    bucket_totals<<<N_BUCKETS, 256, 0, stream>>>(counts, tot);
    scan_buckets<<<1, 1024, 0, stream>>>(tot, bbase, N_BUCKETS);
    column_scan<<<N_BUCKETS, 512, 0, stream>>>(counts, bbase, offs);
    block_scatter<<<NCHUNK, 256, 0, stream>>>(src, dst, offs, records, N_EDGES);
    bucket_csr<<<N_BUCKETS, 512, 0, stream>>>(records, bbase, ptr, dinv, csr_src, N_NODES);

    // ---- conversions / weight packing ----
    convert_x_pre<<<(N_NODES * (F_IN / 4) + 255) / 256, 256, 0, stream>>>(x, dinv, x_pre, N_NODES);
    pack_w<<<(F_IN * HDIM + 255) / 256, 256, 0, stream>>>(W1, W1hi, W1lo, F_IN);
    pack_w<<<(HDIM * HDIM + 255) / 256, 256, 0, stream>>>(W2, W2hi, W2lo, HDIM);

    // ---- layer 1 ----
    csr_agg128_bf16<<<(N_NODES + 3) / 4, 256, 0, stream>>>(x_pre, ptr, csr_src, dinv, A1, N_NODES);
    gemm_mfma<F_IN, true><<<(N_NODES + 127) / 128, 256, 0, stream>>>(A1, W1hi, W1lo, b1, dinv,
                                                                     h1_pre, N_NODES);
    // ---- layer 2 ----
    csr_agg256_bf16<<<(N_NODES + 3) / 4, 256, 0, stream>>>(h1_pre, ptr, csr_src, dinv, A2, N_NODES);
    gemm_mfma<HDIM, false><<<(N_NODES + 127) / 128, 256, 0, stream>>>(A2, W2hi, W2lo, b2, dinv,
                                                                      h2, N_NODES);

    // ---- pool + head ----
    zero_f<<<(N_GRAPHS * HDIM + N_GRAPHS + 255) / 256, 256, 0, stream>>>(
        pool, N_GRAPHS * HDIM + N_GRAPHS);
    pool_sum_runs<<<(N_NODES + 127) / 128, 256, 0, stream>>>(h2, batch, pool, cnt, N_NODES);
    final_head<<<1, 64, 0, stream>>>(pool, cnt, fcw, fcb, out);
}

// Round 7
// 957.404 us; speedup vs baseline: 2.5336x; 1.1070x over previous
//
#include <hip/hip_runtime.h>
#include <cstdint>

#define N_NODES 100000
#define N_EDGES 3200000
#define N_GRAPHS 64
#define HDIM 256
#define F_IN 128

#define BUCKET_BITS 7
#define NPB 128                                 // nodes per bucket
#define N_BUCKETS ((N_NODES + NPB - 1) / NPB)   // 782
#define CHUNK 8192
#define NCHUNK ((N_EDGES + CHUNK - 1) / CHUNK)  // 391

typedef __attribute__((ext_vector_type(8))) short bf16x8;
typedef __attribute__((ext_vector_type(4))) float f32x4;
typedef __attribute__((ext_vector_type(2))) float f32x2;

// ---------------- bf16 helpers ----------------
__device__ __forceinline__ unsigned short f2bf(float f) {
    unsigned int b = __float_as_uint(f);
    b = (b + 0x7FFFu + ((b >> 16) & 1u)) >> 16;
    return (unsigned short)b;
}

// ---------------- fp8 e4m3 helpers (HW cvt) ----------------
__device__ __forceinline__ unsigned int pack4_fp8(float a, float b, float c, float d) {
    int v = 0;
    v = __builtin_amdgcn_cvt_pk_fp8_f32(a, b, v, false);  // bytes 0,1
    v = __builtin_amdgcn_cvt_pk_fp8_f32(c, d, v, true);   // bytes 2,3
    return (unsigned int)v;
}
__device__ __forceinline__ unsigned char pack1_fp8(float a) {
    int v = __builtin_amdgcn_cvt_pk_fp8_f32(a, a, 0, false);
    return (unsigned char)(v & 0xFF);
}

// ---------------- utility ----------------
__global__ void zero_f(float* p, int n) {
    int i = blockIdx.x * blockDim.x + threadIdx.x;
    if (i < n) p[i] = 0.0f;
}

// ---------------- atomic-free multisplit CSR build ----------------
__global__ __launch_bounds__(256) void block_count(const int* __restrict__ dst,
                                                   int* __restrict__ counts, int nE) {
    __shared__ int hist[N_BUCKETS];
    int blk = blockIdx.x, t = threadIdx.x;
    for (int i = t; i < N_BUCKETS; i += 256) hist[i] = 0;
    __syncthreads();
    int lo = blk * CHUNK;
    int hi = lo + CHUNK < nE ? lo + CHUNK : nE;
    for (int i = lo + t; i < hi; i += 256) atomicAdd(&hist[dst[i] >> BUCKET_BITS], 1);
    __syncthreads();
    for (int i = t; i < N_BUCKETS; i += 256) counts[blk * N_BUCKETS + i] = hist[i];
}

__global__ __launch_bounds__(256) void bucket_totals(const int* __restrict__ counts,
                                                     int* __restrict__ tot) {
    __shared__ int red[256];
    int b = blockIdx.x, t = threadIdx.x;
    int s = 0;
    for (int blk = t; blk < NCHUNK; blk += 256) s += counts[blk * N_BUCKETS + b];
    red[t] = s;
    __syncthreads();
    for (int o = 128; o > 0; o >>= 1) {
        if (t < o) red[t] += red[t + o];
        __syncthreads();
    }
    if (t == 0) tot[b] = red[0];
}

__global__ __launch_bounds__(1024) void scan_buckets(const int* __restrict__ tot,
                                                     int* __restrict__ base, int nb) {
    __shared__ int lds[1024];
    int t = threadIdx.x;
    int v = (t < nb) ? tot[t] : 0;
    lds[t] = v;
    __syncthreads();
    for (int off = 1; off < 1024; off <<= 1) {
        int a = (t >= off) ? lds[t - off] : 0;
        __syncthreads();
        lds[t] += a;
        __syncthreads();
    }
    int excl = lds[t] - v;
    if (t < nb) base[t] = excl;
    if (t == nb) base[t] = excl;
}

__global__ __launch_bounds__(512) void column_scan(const int* __restrict__ counts,
                                                   const int* __restrict__ base,
                                                   int* __restrict__ offs) {
    __shared__ int lds[512];
    int b = blockIdx.x, t = threadIdx.x;
    int v = (t < NCHUNK) ? counts[t * N_BUCKETS + b] : 0;
    lds[t] = v;
    __syncthreads();
    for (int off = 1; off < 512; off <<= 1) {
        int a = (t >= off) ? lds[t - off] : 0;
        __syncthreads();
        lds[t] += a;
        __syncthreads();
    }
    if (t < NCHUNK) offs[t * N_BUCKETS + b] = base[b] + lds[t] - v;
}

__global__ __launch_bounds__(256) void block_scatter(const int* __restrict__ src,
                                                     const int* __restrict__ dst,
                                                     const int* __restrict__ offs,
                                                     unsigned int* __restrict__ rec, int nE) {
    __shared__ int cur[N_BUCKETS];
    int blk = blockIdx.x, t = threadIdx.x;
    for (int i = t; i < N_BUCKETS; i += 256) cur[i] = offs[blk * N_BUCKETS + i];
    __syncthreads();
    int lo = blk * CHUNK;
    int hi = lo + CHUNK < nE ? lo + CHUNK : nE;
    for (int i = lo + t; i < hi; i += 256) {
        int d = dst[i];
        int b = d >> BUCKET_BITS;
        int pos = atomicAdd(&cur[b], 1);  // LDS atomic
        rec[pos] = (unsigned int)src[i] | ((unsigned int)(d & (NPB - 1)) << 17);
    }
}

__global__ __launch_bounds__(512) void bucket_csr(const unsigned int* __restrict__ rec,
                                                  const int* __restrict__ base,
                                                  int* __restrict__ ptr, float* __restrict__ dinv,
                                                  int* __restrict__ csr_src, int n) {
    __shared__ int hist[NPB];
    __shared__ int sc[NPB];
    __shared__ int cur[NPB];
    int b = blockIdx.x;
    int lo = base[b], hi = base[b + 1];
    int t = threadIdx.x;
    if (t < NPB) hist[t] = 0;
    __syncthreads();
    for (int i = lo + t; i < hi; i += 512) atomicAdd(&hist[rec[i] >> 17], 1);
    __syncthreads();
    if (t < NPB) sc[t] = hist[t];
    __syncthreads();
    for (int off = 1; off < NPB; off <<= 1) {
        int a = (t < NPB && t >= off) ? sc[t - off] : 0;
        __syncthreads();
        if (t < NPB) sc[t] += a;
        __syncthreads();
    }
    if (t < NPB) {
        int node = b * NPB + t;
        int incl = sc[t];
        int excl = incl - hist[t];
        if (node < n) {
            ptr[node] = lo + incl;
            dinv[node] = rsqrtf((float)hist[t] + 1.0f);
        }
        cur[t] = lo + excl;
    }
    __syncthreads();
    for (int i = lo + t; i < hi; i += 512) {
        unsigned int r = rec[i];
        int pos = atomicAdd(&cur[r >> 17], 1);
        csr_src[pos] = (int)(r & 0x1FFFFu);
    }
}

// ---------------- x -> fp8 pre-scaled: x_pre[n] = fp8(dinv[n] * x[n]) ----------------
__global__ void convert_x_pre(const float* __restrict__ x, const float* __restrict__ dinv,
                              unsigned int* __restrict__ xp, int n) {
    int tid = blockIdx.x * blockDim.x + threadIdx.x;  // over n*F_IN/4
    if (tid >= n * (F_IN / 4)) return;
    int node = tid / (F_IN / 4);
    float di = dinv[node];
    float4 v = ((const float4*)x)[tid];
    xp[tid] = pack4_fp8(v.x * di, v.y * di, v.z * di, v.w * di);
}

// ---------------- pack W[K][256] fp32 -> hi/lo bf16 in MFMA B-fragment order ----------------
__global__ void pack_w(const float* __restrict__ W, unsigned short* __restrict__ hi,
                       unsigned short* __restrict__ lo, int K) {
    int idx = blockIdx.x * blockDim.x + threadIdx.x;
    if (idx >= K * HDIM) return;
    int k = idx >> 8, c = idx & 255;
    float w = W[idx];
    unsigned short h = f2bf(w);
    float hf = __uint_as_float((unsigned int)h << 16);
    unsigned short l = f2bf(w - hf);
    int pos = ((k >> 5) * 16 + (c >> 4)) * 512 + ((((k >> 3) & 3) * 16) + (c & 15)) * 8 + (k & 7);
    hi[pos] = h;
    lo[pos] = l;
}

// ---------------- aggregation (fp8 in, bf16 out) ----------------
// out[d] = bf16( dinv[d] * ( h_pre[d] + sum_s h_pre[s] ) ), h_pre already dinv-scaled
__global__ void csr_agg128_fp8(const unsigned char* __restrict__ h, const int* __restrict__ ptr,
                               const int* __restrict__ csr, const float* __restrict__ dinv,
                               unsigned short* __restrict__ out, int n) {
    int wave = threadIdx.x >> 6, lane = threadIdx.x & 63;
    int node = blockIdx.x * 4 + wave;
    if (node >= n) return;
    int begin = node ? ptr[node - 1] : 0;
    int end = ptr[node];
    unsigned int u = *(const unsigned short*)(h + (size_t)node * 128 + lane * 2);
    f32x2 v = __builtin_amdgcn_cvt_pk_f32_fp8((int)u, false);
    float a0 = v.x, a1 = v.y;
    int i = begin;
    for (; i + 1 < end; i += 2) {
        int s0 = csr[i], s1 = csr[i + 1];
        unsigned int u0 = *(const unsigned short*)(h + (size_t)s0 * 128 + lane * 2);
        unsigned int u1 = *(const unsigned short*)(h + (size_t)s1 * 128 + lane * 2);
        f32x2 v0 = __builtin_amdgcn_cvt_pk_f32_fp8((int)u0, false);
        f32x2 v1 = __builtin_amdgcn_cvt_pk_f32_fp8((int)u1, false);
        a0 += v0.x + v1.x;
        a1 += v0.y + v1.y;
    }
    if (i < end) {
        int s = csr[i];
        unsigned int u0 = *(const unsigned short*)(h + (size_t)s * 128 + lane * 2);
        f32x2 v0 = __builtin_amdgcn_cvt_pk_f32_fp8((int)u0, false);
        a0 += v0.x; a1 += v0.y;
    }
    float dn = dinv[node];
    unsigned int o = (unsigned int)f2bf(a0 * dn) | ((unsigned int)f2bf(a1 * dn) << 16);
    *(unsigned int*)(out + (size_t)node * 128 + lane * 2) = o;
}

__global__ void csr_agg256_fp8(const unsigned char* __restrict__ h, const int* __restrict__ ptr,
                               const int* __restrict__ csr, const float* __restrict__ dinv,
                               unsigned short* __restrict__ out, int n) {
    int wave = threadIdx.x >> 6, lane = threadIdx.x & 63;
    int node = blockIdx.x * 4 + wave;
    if (node >= n) return;
    int begin = node ? ptr[node - 1] : 0;
    int end = ptr[node];
    unsigned int u = *(const unsigned int*)(h + (size_t)node * 256 + lane * 4);
    f32x2 vl = __builtin_amdgcn_cvt_pk_f32_fp8((int)u, false);
    f32x2 vh = __builtin_amdgcn_cvt_pk_f32_fp8((int)u, true);
    float a0 = vl.x, a1 = vl.y, a2 = vh.x, a3 = vh.y;
    int i = begin;
    for (; i + 1 < end; i += 2) {
        int s0 = csr[i], s1 = csr[i + 1];
        unsigned int u0 = *(const unsigned int*)(h + (size_t)s0 * 256 + lane * 4);
        unsigned int u1 = *(const unsigned int*)(h + (size_t)s1 * 256 + lane * 4);
        f32x2 l0 = __builtin_amdgcn_cvt_pk_f32_fp8((int)u0, false);
        f32x2 h0 = __builtin_amdgcn_cvt_pk_f32_fp8((int)u0, true);
        f32x2 l1 = __builtin_amdgcn_cvt_pk_f32_fp8((int)u1, false);
        f32x2 h1 = __builtin_amdgcn_cvt_pk_f32_fp8((int)u1, true);
        a0 += l0.x + l1.x;
        a1 += l0.y + l1.y;
        a2 += h0.x + h1.x;
        a3 += h0.y + h1.y;
    }
    if (i < end) {
        int s = csr[i];
        unsigned int u0 = *(const unsigned int*)(h + (size_t)s * 256 + lane * 4);
        f32x2 l0 = __builtin_amdgcn_cvt_pk_f32_fp8((int)u0, false);
        f32x2 h0 = __builtin_amdgcn_cvt_pk_f32_fp8((int)u0, true);
        a0 += l0.x; a1 += l0.y; a2 += h0.x; a3 += h0.y;
    }
    float dn = dinv[node];
    uint2 o;
    o.x = (unsigned int)f2bf(a0 * dn) | ((unsigned int)f2bf(a1 * dn) << 16);
    o.y = (unsigned int)f2bf(a2 * dn) | ((unsigned int)f2bf(a3 * dn) << 16);
    *(uint2*)(out + (size_t)node * 256 + lane * 4) = o;
}

// ---------------- MFMA GEMM: out[n,256] = act(A[n,K] @ (Whi+Wlo) + b) ----------------
// PRESCALE: out fp8 = fp8(dinv[row]*relu(v));  else: out fp32 = relu(v)
template <int K, bool PRESCALE>
__global__ __launch_bounds__(256) void gemm_mfma(
    const unsigned short* __restrict__ A, const unsigned short* __restrict__ Whi,
    const unsigned short* __restrict__ Wlo, const float* __restrict__ bias,
    const float* __restrict__ dinv, void* __restrict__ outp, int n) {
    int wave = threadIdx.x >> 6, lane = threadIdx.x & 63;
    int quad = lane >> 4, l16 = lane & 15;
    int rowbase = blockIdx.x * 128 + wave * 32;

    f32x4 acc[2][16];
#pragma unroll
    for (int s = 0; s < 2; s++)
#pragma unroll
        for (int ct = 0; ct < 16; ct++) acc[s][ct] = (f32x4){0.f, 0.f, 0.f, 0.f};

    int r0 = rowbase + l16;
    int r1 = rowbase + 16 + l16;
    int rc0 = r0 < n ? r0 : n - 1;
    int rc1 = r1 < n ? r1 : n - 1;

    for (int kt = 0; kt < K / 32; kt++) {
        bf16x8 a0 = *(const bf16x8*)(A + (size_t)rc0 * K + kt * 32 + quad * 8);
        bf16x8 a1 = *(const bf16x8*)(A + (size_t)rc1 * K + kt * 32 + quad * 8);
        const unsigned short* wh = Whi + (size_t)kt * 16 * 512;
        const unsigned short* wl = Wlo + (size_t)kt * 16 * 512;
#pragma unroll
        for (int ct = 0; ct < 16; ct++) {
            bf16x8 bh = *(const bf16x8*)(wh + ct * 512 + lane * 8);
            bf16x8 bl = *(const bf16x8*)(wl + ct * 512 + lane * 8);
            acc[0][ct] = __builtin_amdgcn_mfma_f32_16x16x32_bf16(a0, bh, acc[0][ct], 0, 0, 0);
            acc[0][ct] = __builtin_amdgcn_mfma_f32_16x16x32_bf16(a0, bl, acc[0][ct], 0, 0, 0);
            acc[1][ct] = __builtin_amdgcn_mfma_f32_16x16x32_bf16(a1, bh, acc[1][ct], 0, 0, 0);
            acc[1][ct] = __builtin_amdgcn_mfma_f32_16x16x32_bf16(a1, bl, acc[1][ct], 0, 0, 0);
        }
    }

#pragma unroll
    for (int s = 0; s < 2; s++) {
#pragma unroll
        for (int ct = 0; ct < 16; ct++) {
            int col = ct * 16 + l16;
            float b = bias[col];
#pragma unroll
            for (int r = 0; r < 4; r++) {
                int row = rowbase + s * 16 + quad * 4 + r;
                if (row < n) {
                    float v = acc[s][ct][r] + b;
                    v = v > 0.0f ? v : 0.0f;
                    if (PRESCALE) {
                        ((unsigned char*)outp)[(size_t)row * HDIM + col] = pack1_fp8(v * dinv[row]);
                    } else {
                        ((float*)outp)[(size_t)row * HDIM + col] = v;
                    }
                }
            }
        }
    }
}

// ---------------- pooling (batch sorted -> run-length) ----------------
__global__ void pool_sum_runs(const float* __restrict__ h, const int* __restrict__ batch,
                              float* __restrict__ pool, float* __restrict__ cnt, int n) {
    constexpr int ROWS = 128;
    int f = threadIdx.x;
    int r0 = blockIdx.x * ROWS;
    int rend = r0 + ROWS;
    if (rend > n) rend = n;
    float acc = 0.0f;
    int cur = batch[r0];
    int runlen = 0;
    for (int r = r0; r < rend; r++) {
        int g = batch[r];
        if (g != cur) {
            atomicAdd(&pool[cur * HDIM + f], acc);
            if (f == 0) atomicAdd(&cnt[cur], (float)runlen);
            acc = 0.0f; runlen = 0; cur = g;
        }
        acc += h[(size_t)r * HDIM + f];
        runlen++;
    }
    atomicAdd(&pool[cur * HDIM + f], acc);
    if (f == 0) atomicAdd(&cnt[cur], (float)runlen);
}

__global__ void final_head(const float* __restrict__ pool, const float* __restrict__ cnt,
                           const float* __restrict__ fcw, const float* __restrict__ fcb,
                           float* __restrict__ out) {
    int g = threadIdx.x;
    if (g < N_GRAPHS) {
        float c = cnt[g];
        c = c > 1.0f ? c : 1.0f;
        float inv = 1.0f / c;
        float l0 = fcb[0], l1 = fcb[1];
        for (int f = 0; f < HDIM; f++) {
            float p = pool[g * HDIM + f] * inv;
            l0 += p * fcw[f * 2 + 0];
            l1 += p * fcw[f * 2 + 1];
        }
        float m = fmaxf(l0, l1);
        float lse = m + logf(expf(l0 - m) + expf(l1 - m));
        out[g * 2 + 0] = l0 - lse;
        out[g * 2 + 1] = l1 - lse;
    }
}

extern "C" void kernel_launch(void* const* d_in, const int* in_sizes, int n_in,
                              void* d_out, int out_size, void* d_ws, size_t ws_size,
                              hipStream_t stream) {
    const float* x = (const float*)d_in[0];
    const int* ei = (const int*)d_in[1];
    const int* batch = (const int*)d_in[2];
    const float* W1 = (const float*)d_in[3];
    const float* b1 = (const float*)d_in[4];
    const float* W2 = (const float*)d_in[5];
    const float* b2 = (const float*)d_in[6];
    const float* fcw = (const float*)d_in[7];
    const float* fcb = (const float*)d_in[8];
    float* out = (float*)d_out;

    const int* src = ei;
    const int* dst = ei + N_EDGES;

    // ---- workspace layout (bytes) ----
    char* ws = (char*)d_ws;
    float* dinv = (float*)ws;            ws += 4 * ((N_NODES + 255) & ~255);
    int* ptr = (int*)ws;                 ws += 4 * ((N_NODES + 255) & ~255);
    int* csr_src = (int*)ws;             ws += 4 * (size_t)N_EDGES;
    int* counts = (int*)ws;              ws += 4 * (size_t)NCHUNK * N_BUCKETS;
    int* offs = (int*)ws;                ws += 4 * (size_t)NCHUNK * N_BUCKETS;
    int* tot = (int*)ws;                 ws += 4 * 1024;
    int* bbase = (int*)ws;               ws += 4 * 1024;
    unsigned short* W1hi = (unsigned short*)ws; ws += 2 * F_IN * HDIM;
    unsigned short* W1lo = (unsigned short*)ws; ws += 2 * F_IN * HDIM;
    unsigned short* W2hi = (unsigned short*)ws; ws += 2 * HDIM * HDIM;
    unsigned short* W2lo = (unsigned short*)ws; ws += 2 * HDIM * HDIM;
    float* pool = (float*)ws;            ws += 4 * N_GRAPHS * HDIM;
    float* cnt = (float*)ws;             ws += 4 * ((N_GRAPHS + 63) & ~63);
    // R0 region (N*HDIM*4 = 102.4MB): x_pre fp8 | A1 bf16 | h1_pre fp8; reused as h2 fp32
    char* R0 = ws;                       ws += 4 * (size_t)N_NODES * HDIM;
    unsigned char* x_pre = (unsigned char*)R0;                                 // N*128 fp8
    unsigned short* A1 = (unsigned short*)(R0 + (size_t)N_NODES * F_IN);       // N*128 bf16
    unsigned char* h1_pre = (unsigned char*)(R0 + 3 * (size_t)N_NODES * F_IN); // N*256 fp8
    float* h2 = (float*)R0;                                                    // N*256 fp32
    unsigned short* A2 = (unsigned short*)ws;  // N*256 bf16 (layer 2 only)
    // records overlay A2 (dead until layer 2): N_EDGES*4 = 12.8MB <= 51.2MB
    unsigned int* records = (unsigned int*)A2;

    // ---- atomic-free bucketed CSR build + dinv ----
    block_count<<<NCHUNK, 256, 0, stream>>>(dst, counts, N_EDGES);
    bucket_totals<<<N_BUCKETS, 256, 0, stream>>>(counts, tot);
    scan_buckets<<<1, 1024, 0, stream>>>(tot, bbase, N_BUCKETS);
    column_scan<<<N_BUCKETS, 512, 0, stream>>>(counts, bbase, offs);
    block_scatter<<<NCHUNK, 256, 0, stream>>>(src, dst, offs, records, N_EDGES);
    bucket_csr<<<N_BUCKETS, 512, 0, stream>>>(records, bbase, ptr, dinv, csr_src, N_NODES);

    // ---- conversions / weight packing ----
    convert_x_pre<<<(N_NODES * (F_IN / 4) + 255) / 256, 256, 0, stream>>>(
        x, dinv, (unsigned int*)x_pre, N_NODES);
    pack_w<<<(F_IN * HDIM + 255) / 256, 256, 0, stream>>>(W1, W1hi, W1lo, F_IN);
    pack_w<<<(HDIM * HDIM + 255) / 256, 256, 0, stream>>>(W2, W2hi, W2lo, HDIM);

    // ---- layer 1 ----
    csr_agg128_fp8<<<(N_NODES + 3) / 4, 256, 0, stream>>>(x_pre, ptr, csr_src, dinv, A1, N_NODES);
    gemm_mfma<F_IN, true><<<(N_NODES + 127) / 128, 256, 0, stream>>>(A1, W1hi, W1lo, b1, dinv,
                                                                     h1_pre, N_NODES);
    // ---- layer 2 ----
    csr_agg256_fp8<<<(N_NODES + 3) / 4, 256, 0, stream>>>(h1_pre, ptr, csr_src, dinv, A2, N_NODES);
    gemm_mfma<HDIM, false><<<(N_NODES + 127) / 128, 256, 0, stream>>>(A2, W2hi, W2lo, b2, dinv,
                                                                      h2, N_NODES);

    // ---- pool + head ----
    zero_f<<<(N_GRAPHS * HDIM + N_GRAPHS + 255) / 256, 256, 0, stream>>>(
        pool, N_GRAPHS * HDIM + N_GRAPHS);
    pool_sum_runs<<<(N_NODES + 127) / 128, 256, 0, stream>>>(h2, batch, pool, cnt, N_NODES);
    final_head<<<1, 64, 0, stream>>>(pool, cnt, fcw, fcb, out);
}

// Round 8
// 768.000 us; speedup vs baseline: 3.1584x; 1.2466x over previous
//
#include <hip/hip_runtime.h>
#include <cstdint>

#define N_NODES 100000
#define N_EDGES 3200000
#define N_GRAPHS 64
#define HDIM 256
#define F_IN 128

#define BUCKET_BITS 7
#define NPB 128                                 // nodes per bucket
#define N_BUCKETS ((N_NODES + NPB - 1) / NPB)   // 782
#define CHUNK 8192
#define NCHUNK ((N_EDGES + CHUNK - 1) / CHUNK)  // 391

typedef __attribute__((ext_vector_type(8))) short bf16x8;
typedef __attribute__((ext_vector_type(4))) float f32x4;
typedef __attribute__((ext_vector_type(2))) float f32x2;

// ---------------- bf16 helpers ----------------
__device__ __forceinline__ unsigned short f2bf(float f) {
    unsigned int b = __float_as_uint(f);
    b = (b + 0x7FFFu + ((b >> 16) & 1u)) >> 16;
    return (unsigned short)b;
}

// ---------------- fp8 e4m3 helpers (HW cvt) ----------------
__device__ __forceinline__ unsigned int pack4_fp8(float a, float b, float c, float d) {
    int v = 0;
    v = __builtin_amdgcn_cvt_pk_fp8_f32(a, b, v, false);  // bytes 0,1
    v = __builtin_amdgcn_cvt_pk_fp8_f32(c, d, v, true);   // bytes 2,3
    return (unsigned int)v;
}
__device__ __forceinline__ unsigned char pack1_fp8(float a) {
    int v = __builtin_amdgcn_cvt_pk_fp8_f32(a, a, 0, false);
    return (unsigned char)(v & 0xFF);
}

// ---------------- utility ----------------
__global__ void zero_f(float* p, int n) {
    int i = blockIdx.x * blockDim.x + threadIdx.x;
    if (i < n) p[i] = 0.0f;
}

// ---------------- atomic-free multisplit CSR build ----------------
__global__ __launch_bounds__(256) void block_count(const int* __restrict__ dst,
                                                   int* __restrict__ counts, int nE) {
    __shared__ int hist[N_BUCKETS];
    int blk = blockIdx.x, t = threadIdx.x;
    for (int i = t; i < N_BUCKETS; i += 256) hist[i] = 0;
    __syncthreads();
    int lo = blk * CHUNK;
    int hi = lo + CHUNK < nE ? lo + CHUNK : nE;
    for (int i = lo + t; i < hi; i += 256) atomicAdd(&hist[dst[i] >> BUCKET_BITS], 1);
    __syncthreads();
    for (int i = t; i < N_BUCKETS; i += 256) counts[blk * N_BUCKETS + i] = hist[i];
}

__global__ __launch_bounds__(256) void bucket_totals(const int* __restrict__ counts,
                                                     int* __restrict__ tot) {
    __shared__ int red[256];
    int b = blockIdx.x, t = threadIdx.x;
    int s = 0;
    for (int blk = t; blk < NCHUNK; blk += 256) s += counts[blk * N_BUCKETS + b];
    red[t] = s;
    __syncthreads();
    for (int o = 128; o > 0; o >>= 1) {
        if (t < o) red[t] += red[t + o];
        __syncthreads();
    }
    if (t == 0) tot[b] = red[0];
}

__global__ __launch_bounds__(1024) void scan_buckets(const int* __restrict__ tot,
                                                     int* __restrict__ base, int nb) {
    __shared__ int lds[1024];
    int t = threadIdx.x;
    int v = (t < nb) ? tot[t] : 0;
    lds[t] = v;
    __syncthreads();
    for (int off = 1; off < 1024; off <<= 1) {
        int a = (t >= off) ? lds[t - off] : 0;
        __syncthreads();
        lds[t] += a;
        __syncthreads();
    }
    int excl = lds[t] - v;
    if (t < nb) base[t] = excl;
    if (t == nb) base[t] = excl;
}

__global__ __launch_bounds__(512) void column_scan(const int* __restrict__ counts,
                                                   const int* __restrict__ base,
                                                   int* __restrict__ offs) {
    __shared__ int lds[512];
    int b = blockIdx.x, t = threadIdx.x;
    int v = (t < NCHUNK) ? counts[t * N_BUCKETS + b] : 0;
    lds[t] = v;
    __syncthreads();
    for (int off = 1; off < 512; off <<= 1) {
        int a = (t >= off) ? lds[t - off] : 0;
        __syncthreads();
        lds[t] += a;
        __syncthreads();
    }
    if (t < NCHUNK) offs[t * N_BUCKETS + b] = base[b] + lds[t] - v;
}

__global__ __launch_bounds__(256) void block_scatter(const int* __restrict__ src,
                                                     const int* __restrict__ dst,
                                                     const int* __restrict__ offs,
                                                     unsigned int* __restrict__ rec, int nE) {
    __shared__ int cur[N_BUCKETS];
    int blk = blockIdx.x, t = threadIdx.x;
    for (int i = t; i < N_BUCKETS; i += 256) cur[i] = offs[blk * N_BUCKETS + i];
    __syncthreads();
    int lo = blk * CHUNK;
    int hi = lo + CHUNK < nE ? lo + CHUNK : nE;
    for (int i = lo + t; i < hi; i += 256) {
        int d = dst[i];
        int b = d >> BUCKET_BITS;
        int pos = atomicAdd(&cur[b], 1);  // LDS atomic
        rec[pos] = (unsigned int)src[i] | ((unsigned int)(d & (NPB - 1)) << 17);
    }
}

__global__ __launch_bounds__(512) void bucket_csr(const unsigned int* __restrict__ rec,
                                                  const int* __restrict__ base,
                                                  int* __restrict__ ptr, float* __restrict__ dinv,
                                                  int* __restrict__ csr_src, int n) {
    __shared__ int hist[NPB];
    __shared__ int sc[NPB];
    __shared__ int cur[NPB];
    int b = blockIdx.x;
    int lo = base[b], hi = base[b + 1];
    int t = threadIdx.x;
    if (t < NPB) hist[t] = 0;
    __syncthreads();
    for (int i = lo + t; i < hi; i += 512) atomicAdd(&hist[rec[i] >> 17], 1);
    __syncthreads();
    if (t < NPB) sc[t] = hist[t];
    __syncthreads();
    for (int off = 1; off < NPB; off <<= 1) {
        int a = (t < NPB && t >= off) ? sc[t - off] : 0;
        __syncthreads();
        if (t < NPB) sc[t] += a;
        __syncthreads();
    }
    if (t < NPB) {
        int node = b * NPB + t;
        int incl = sc[t];
        int excl = incl - hist[t];
        if (node < n) {
            ptr[node] = lo + incl;
            dinv[node] = rsqrtf((float)hist[t] + 1.0f);
        }
        cur[t] = lo + excl;
    }
    __syncthreads();
    for (int i = lo + t; i < hi; i += 512) {
        unsigned int r = rec[i];
        int pos = atomicAdd(&cur[r >> 17], 1);
        csr_src[pos] = (int)(r & 0x1FFFFu);
    }
}

// ---------------- x -> fp8 pre-scaled: x_pre[n] = fp8(dinv[n] * x[n]) ----------------
__global__ void convert_x_pre(const float* __restrict__ x, const float* __restrict__ dinv,
                              unsigned int* __restrict__ xp, int n) {
    int tid = blockIdx.x * blockDim.x + threadIdx.x;  // over n*F_IN/4
    if (tid >= n * (F_IN / 4)) return;
    int node = tid / (F_IN / 4);
    float di = dinv[node];
    float4 v = ((const float4*)x)[tid];
    xp[tid] = pack4_fp8(v.x * di, v.y * di, v.z * di, v.w * di);
}

// ---------------- pack W[K][256] fp32 -> hi/lo bf16 in MFMA B-fragment order ----------------
__global__ void pack_w(const float* __restrict__ W, unsigned short* __restrict__ hi,
                       unsigned short* __restrict__ lo, int K) {
    int idx = blockIdx.x * blockDim.x + threadIdx.x;
    if (idx >= K * HDIM) return;
    int k = idx >> 8, c = idx & 255;
    float w = W[idx];
    unsigned short h = f2bf(w);
    float hf = __uint_as_float((unsigned int)h << 16);
    unsigned short l = f2bf(w - hf);
    int pos = ((k >> 5) * 16 + (c >> 4)) * 512 + ((((k >> 3) & 3) * 16) + (c & 15)) * 8 + (k & 7);
    hi[pos] = h;
    lo[pos] = l;
}

// ---------------- aggregation (fp8 in, bf16 out) ----------------
__global__ void csr_agg128_fp8(const unsigned char* __restrict__ h, const int* __restrict__ ptr,
                               const int* __restrict__ csr, const float* __restrict__ dinv,
                               unsigned short* __restrict__ out, int n) {
    int wave = threadIdx.x >> 6, lane = threadIdx.x & 63;
    int node = blockIdx.x * 4 + wave;
    if (node >= n) return;
    int begin = node ? ptr[node - 1] : 0;
    int end = ptr[node];
    unsigned int u = *(const unsigned short*)(h + (size_t)node * 128 + lane * 2);
    f32x2 v = __builtin_amdgcn_cvt_pk_f32_fp8((int)u, false);
    float a0 = v.x, a1 = v.y;
    int i = begin;
    for (; i + 1 < end; i += 2) {
        int s0 = csr[i], s1 = csr[i + 1];
        unsigned int u0 = *(const unsigned short*)(h + (size_t)s0 * 128 + lane * 2);
        unsigned int u1 = *(const unsigned short*)(h + (size_t)s1 * 128 + lane * 2);
        f32x2 v0 = __builtin_amdgcn_cvt_pk_f32_fp8((int)u0, false);
        f32x2 v1 = __builtin_amdgcn_cvt_pk_f32_fp8((int)u1, false);
        a0 += v0.x + v1.x;
        a1 += v0.y + v1.y;
    }
    if (i < end) {
        int s = csr[i];
        unsigned int u0 = *(const unsigned short*)(h + (size_t)s * 128 + lane * 2);
        f32x2 v0 = __builtin_amdgcn_cvt_pk_f32_fp8((int)u0, false);
        a0 += v0.x; a1 += v0.y;
    }
    float dn = dinv[node];
    unsigned int o = (unsigned int)f2bf(a0 * dn) | ((unsigned int)f2bf(a1 * dn) << 16);
    *(unsigned int*)(out + (size_t)node * 128 + lane * 2) = o;
}

__global__ void csr_agg256_fp8(const unsigned char* __restrict__ h, const int* __restrict__ ptr,
                               const int* __restrict__ csr, const float* __restrict__ dinv,
                               unsigned short* __restrict__ out, int n) {
    int wave = threadIdx.x >> 6, lane = threadIdx.x & 63;
    int node = blockIdx.x * 4 + wave;
    if (node >= n) return;
    int begin = node ? ptr[node - 1] : 0;
    int end = ptr[node];
    unsigned int u = *(const unsigned int*)(h + (size_t)node * 256 + lane * 4);
    f32x2 vl = __builtin_amdgcn_cvt_pk_f32_fp8((int)u, false);
    f32x2 vh = __builtin_amdgcn_cvt_pk_f32_fp8((int)u, true);
    float a0 = vl.x, a1 = vl.y, a2 = vh.x, a3 = vh.y;
    int i = begin;
    for (; i + 1 < end; i += 2) {
        int s0 = csr[i], s1 = csr[i + 1];
        unsigned int u0 = *(const unsigned int*)(h + (size_t)s0 * 256 + lane * 4);
        unsigned int u1 = *(const unsigned int*)(h + (size_t)s1 * 256 + lane * 4);
        f32x2 l0 = __builtin_amdgcn_cvt_pk_f32_fp8((int)u0, false);
        f32x2 h0 = __builtin_amdgcn_cvt_pk_f32_fp8((int)u0, true);
        f32x2 l1 = __builtin_amdgcn_cvt_pk_f32_fp8((int)u1, false);
        f32x2 h1 = __builtin_amdgcn_cvt_pk_f32_fp8((int)u1, true);
        a0 += l0.x + l1.x;
        a1 += l0.y + l1.y;
        a2 += h0.x + h1.x;
        a3 += h0.y + h1.y;
    }
    if (i < end) {
        int s = csr[i];
        unsigned int u0 = *(const unsigned int*)(h + (size_t)s * 256 + lane * 4);
        f32x2 l0 = __builtin_amdgcn_cvt_pk_f32_fp8((int)u0, false);
        f32x2 h0 = __builtin_amdgcn_cvt_pk_f32_fp8((int)u0, true);
        a0 += l0.x; a1 += l0.y; a2 += h0.x; a3 += h0.y;
    }
    float dn = dinv[node];
    uint2 o;
    o.x = (unsigned int)f2bf(a0 * dn) | ((unsigned int)f2bf(a1 * dn) << 16);
    o.y = (unsigned int)f2bf(a2 * dn) | ((unsigned int)f2bf(a3 * dn) << 16);
    *(uint2*)(out + (size_t)node * 256 + lane * 4) = o;
}

// ---------------- MFMA GEMM: out[n,256] = act(A[n,K] @ (Whi+Wlo) + b) ----------------
// block: 4 waves = 64 rows x 256 cols; wave: 32 rows (2 strips) x 128 cols (8 ct)
// acc = 2*8*4 = 64 VGPRs/lane -> 3+ waves/SIMD for latency hiding
// PRESCALE: out fp8 = fp8(dinv[row]*relu(v));  else: out fp32 = relu(v)
template <int K, bool PRESCALE>
__global__ __launch_bounds__(256, 3) void gemm_mfma(
    const unsigned short* __restrict__ A, const unsigned short* __restrict__ Whi,
    const unsigned short* __restrict__ Wlo, const float* __restrict__ bias,
    const float* __restrict__ dinv, void* __restrict__ outp, int n) {
    int wave = threadIdx.x >> 6, lane = threadIdx.x & 63;
    int quad = lane >> 4, l16 = lane & 15;
    int rowgrp = wave >> 1, colhalf = wave & 1;
    int rowbase = blockIdx.x * 64 + rowgrp * 32;

    f32x4 acc[2][8];
#pragma unroll
    for (int s = 0; s < 2; s++)
#pragma unroll
        for (int ct = 0; ct < 8; ct++) acc[s][ct] = (f32x4){0.f, 0.f, 0.f, 0.f};

    int r0 = rowbase + l16;
    int r1 = rowbase + 16 + l16;
    int rc0 = r0 < n ? r0 : n - 1;
    int rc1 = r1 < n ? r1 : n - 1;

    for (int kt = 0; kt < K / 32; kt++) {
        bf16x8 a0 = *(const bf16x8*)(A + (size_t)rc0 * K + kt * 32 + quad * 8);
        bf16x8 a1 = *(const bf16x8*)(A + (size_t)rc1 * K + kt * 32 + quad * 8);
        const unsigned short* wh = Whi + ((size_t)kt * 16 + colhalf * 8) * 512 + lane * 8;
        const unsigned short* wl = Wlo + ((size_t)kt * 16 + colhalf * 8) * 512 + lane * 8;
#pragma unroll
        for (int ct = 0; ct < 8; ct++) {
            bf16x8 bh = *(const bf16x8*)(wh + ct * 512);
            bf16x8 bl = *(const bf16x8*)(wl + ct * 512);
            acc[0][ct] = __builtin_amdgcn_mfma_f32_16x16x32_bf16(a0, bh, acc[0][ct], 0, 0, 0);
            acc[0][ct] = __builtin_amdgcn_mfma_f32_16x16x32_bf16(a0, bl, acc[0][ct], 0, 0, 0);
            acc[1][ct] = __builtin_amdgcn_mfma_f32_16x16x32_bf16(a1, bh, acc[1][ct], 0, 0, 0);
            acc[1][ct] = __builtin_amdgcn_mfma_f32_16x16x32_bf16(a1, bl, acc[1][ct], 0, 0, 0);
        }
    }

#pragma unroll
    for (int s = 0; s < 2; s++) {
#pragma unroll
        for (int ct = 0; ct < 8; ct++) {
            int col = colhalf * 128 + ct * 16 + l16;
            float b = bias[col];
#pragma unroll
            for (int r = 0; r < 4; r++) {
                int row = rowbase + s * 16 + quad * 4 + r;
                if (row < n) {
                    float v = acc[s][ct][r] + b;
                    v = v > 0.0f ? v : 0.0f;
                    if (PRESCALE) {
                        ((unsigned char*)outp)[(size_t)row * HDIM + col] = pack1_fp8(v * dinv[row]);
                    } else {
                        ((float*)outp)[(size_t)row * HDIM + col] = v;
                    }
                }
            }
        }
    }
}

// ---------------- pooling (batch sorted -> run-length) ----------------
__global__ void pool_sum_runs(const float* __restrict__ h, const int* __restrict__ batch,
                              float* __restrict__ pool, float* __restrict__ cnt, int n) {
    constexpr int ROWS = 128;
    int f = threadIdx.x;
    int r0 = blockIdx.x * ROWS;
    int rend = r0 + ROWS;
    if (rend > n) rend = n;
    float acc = 0.0f;
    int cur = batch[r0];
    int runlen = 0;
    for (int r = r0; r < rend; r++) {
        int g = batch[r];
        if (g != cur) {
            atomicAdd(&pool[cur * HDIM + f], acc);
            if (f == 0) atomicAdd(&cnt[cur], (float)runlen);
            acc = 0.0f; runlen = 0; cur = g;
        }
        acc += h[(size_t)r * HDIM + f];
        runlen++;
    }
    atomicAdd(&pool[cur * HDIM + f], acc);
    if (f == 0) atomicAdd(&cnt[cur], (float)runlen);
}

__global__ void final_head(const float* __restrict__ pool, const float* __restrict__ cnt,
                           const float* __restrict__ fcw, const float* __restrict__ fcb,
                           float* __restrict__ out) {
    int g = threadIdx.x;
    if (g < N_GRAPHS) {
        float c = cnt[g];
        c = c > 1.0f ? c : 1.0f;
        float inv = 1.0f / c;
        float l0 = fcb[0], l1 = fcb[1];
        for (int f = 0; f < HDIM; f++) {
            float p = pool[g * HDIM + f] * inv;
            l0 += p * fcw[f * 2 + 0];
            l1 += p * fcw[f * 2 + 1];
        }
        float m = fmaxf(l0, l1);
        float lse = m + logf(expf(l0 - m) + expf(l1 - m));
        out[g * 2 + 0] = l0 - lse;
        out[g * 2 + 1] = l1 - lse;
    }
}

extern "C" void kernel_launch(void* const* d_in, const int* in_sizes, int n_in,
                              void* d_out, int out_size, void* d_ws, size_t ws_size,
                              hipStream_t stream) {
    const float* x = (const float*)d_in[0];
    const int* ei = (const int*)d_in[1];
    const int* batch = (const int*)d_in[2];
    const float* W1 = (const float*)d_in[3];
    const float* b1 = (const float*)d_in[4];
    const float* W2 = (const float*)d_in[5];
    const float* b2 = (const float*)d_in[6];
    const float* fcw = (const float*)d_in[7];
    const float* fcb = (const float*)d_in[8];
    float* out = (float*)d_out;

    const int* src = ei;
    const int* dst = ei + N_EDGES;

    // ---- workspace layout (bytes) ----
    char* ws = (char*)d_ws;
    float* dinv = (float*)ws;            ws += 4 * ((N_NODES + 255) & ~255);
    int* ptr = (int*)ws;                 ws += 4 * ((N_NODES + 255) & ~255);
    int* csr_src = (int*)ws;             ws += 4 * (size_t)N_EDGES;
    int* counts = (int*)ws;              ws += 4 * (size_t)NCHUNK * N_BUCKETS;
    int* offs = (int*)ws;                ws += 4 * (size_t)NCHUNK * N_BUCKETS;
    int* tot = (int*)ws;                 ws += 4 * 1024;
    int* bbase = (int*)ws;               ws += 4 * 1024;
    unsigned short* W1hi = (unsigned short*)ws; ws += 2 * F_IN * HDIM;
    unsigned short* W1lo = (unsigned short*)ws; ws += 2 * F_IN * HDIM;
    unsigned short* W2hi = (unsigned short*)ws; ws += 2 * HDIM * HDIM;
    unsigned short* W2lo = (unsigned short*)ws; ws += 2 * HDIM * HDIM;
    float* pool = (float*)ws;            ws += 4 * N_GRAPHS * HDIM;
    float* cnt = (float*)ws;             ws += 4 * ((N_GRAPHS + 63) & ~63);
    // R0 region (N*HDIM*4 = 102.4MB): x_pre fp8 | A1 bf16 | h1_pre fp8; reused as h2 fp32
    char* R0 = ws;                       ws += 4 * (size_t)N_NODES * HDIM;
    unsigned char* x_pre = (unsigned char*)R0;                                 // N*128 fp8
    unsigned short* A1 = (unsigned short*)(R0 + (size_t)N_NODES * F_IN);       // N*128 bf16
    unsigned char* h1_pre = (unsigned char*)(R0 + 3 * (size_t)N_NODES * F_IN); // N*256 fp8
    float* h2 = (float*)R0;                                                    // N*256 fp32
    unsigned short* A2 = (unsigned short*)ws;  // N*256 bf16 (layer 2 only)
    // records overlay A2 (dead until layer 2): N_EDGES*4 = 12.8MB <= 51.2MB
    unsigned int* records = (unsigned int*)A2;

    // ---- atomic-free bucketed CSR build + dinv ----
    block_count<<<NCHUNK, 256, 0, stream>>>(dst, counts, N_EDGES);
    bucket_totals<<<N_BUCKETS, 256, 0, stream>>>(counts, tot);
    scan_buckets<<<1, 1024, 0, stream>>>(tot, bbase, N_BUCKETS);
    column_scan<<<N_BUCKETS, 512, 0, stream>>>(counts, bbase, offs);
    block_scatter<<<NCHUNK, 256, 0, stream>>>(src, dst, offs, records, N_EDGES);
    bucket_csr<<<N_BUCKETS, 512, 0, stream>>>(records, bbase, ptr, dinv, csr_src, N_NODES);

    // ---- conversions / weight packing ----
    convert_x_pre<<<(N_NODES * (F_IN / 4) + 255) / 256, 256, 0, stream>>>(
        x, dinv, (unsigned int*)x_pre, N_NODES);
    pack_w<<<(F_IN * HDIM + 255) / 256, 256, 0, stream>>>(W1, W1hi, W1lo, F_IN);
    pack_w<<<(HDIM * HDIM + 255) / 256, 256, 0, stream>>>(W2, W2hi, W2lo, HDIM);

    // ---- layer 1 ----
    csr_agg128_fp8<<<(N_NODES + 3) / 4, 256, 0, stream>>>(x_pre, ptr, csr_src, dinv, A1, N_NODES);
    gemm_mfma<F_IN, true><<<(N_NODES + 63) / 64, 256, 0, stream>>>(A1, W1hi, W1lo, b1, dinv,
                                                                   h1_pre, N_NODES);
    // ---- layer 2 ----
    csr_agg256_fp8<<<(N_NODES + 3) / 4, 256, 0, stream>>>(h1_pre, ptr, csr_src, dinv, A2, N_NODES);
    gemm_mfma<HDIM, false><<<(N_NODES + 63) / 64, 256, 0, stream>>>(A2, W2hi, W2lo, b2, dinv,
                                                                    h2, N_NODES);

    // ---- pool + head ----
    zero_f<<<(N_GRAPHS * HDIM + N_GRAPHS + 255) / 256, 256, 0, stream>>>(
        pool, N_GRAPHS * HDIM + N_GRAPHS);
    pool_sum_runs<<<(N_NODES + 127) / 128, 256, 0, stream>>>(h2, batch, pool, cnt, N_NODES);
    final_head<<<1, 64, 0, stream>>>(pool, cnt, fcw, fcb, out);
}

// Round 9
// 661.776 us; speedup vs baseline: 3.6654x; 1.1605x over previous
//
#include <hip/hip_runtime.h>
#include <cstdint>

#define N_NODES 100000
#define N_EDGES 3200000
#define N_GRAPHS 64
#define HDIM 256
#define F_IN 128

#define BUCKET_BITS 7
#define NPB 128                                 // nodes per bucket
#define N_BUCKETS ((N_NODES + NPB - 1) / NPB)   // 782
#define CHUNK 8192
#define NCHUNK ((N_EDGES + CHUNK - 1) / CHUNK)  // 391

typedef __attribute__((ext_vector_type(8))) short bf16x8;
typedef __attribute__((ext_vector_type(4))) float f32x4;
typedef __attribute__((ext_vector_type(2))) float f32x2;

// ---------------- bf16 helpers ----------------
__device__ __forceinline__ unsigned short f2bf(float f) {
    unsigned int b = __float_as_uint(f);
    b = (b + 0x7FFFu + ((b >> 16) & 1u)) >> 16;
    return (unsigned short)b;
}

// ---------------- fp8 e4m3 helpers (HW cvt) ----------------
__device__ __forceinline__ unsigned int pack4_fp8(float a, float b, float c, float d) {
    int v = 0;
    v = __builtin_amdgcn_cvt_pk_fp8_f32(a, b, v, false);  // bytes 0,1
    v = __builtin_amdgcn_cvt_pk_fp8_f32(c, d, v, true);   // bytes 2,3
    return (unsigned int)v;
}
__device__ __forceinline__ unsigned char pack1_fp8(float a) {
    int v = __builtin_amdgcn_cvt_pk_fp8_f32(a, a, 0, false);
    return (unsigned char)(v & 0xFF);
}

// ---------------- utility ----------------
__global__ void zero_f(float* p, int n) {
    int i = blockIdx.x * blockDim.x + threadIdx.x;
    if (i < n) p[i] = 0.0f;
}

// ---------------- atomic-free multisplit CSR build ----------------
__global__ __launch_bounds__(256) void block_count(const int* __restrict__ dst,
                                                   int* __restrict__ counts, int nE) {
    __shared__ int hist[N_BUCKETS];
    int blk = blockIdx.x, t = threadIdx.x;
    for (int i = t; i < N_BUCKETS; i += 256) hist[i] = 0;
    __syncthreads();
    int lo = blk * CHUNK;
    int hi = lo + CHUNK < nE ? lo + CHUNK : nE;
    for (int i = lo + t; i < hi; i += 256) atomicAdd(&hist[dst[i] >> BUCKET_BITS], 1);
    __syncthreads();
    for (int i = t; i < N_BUCKETS; i += 256) counts[blk * N_BUCKETS + i] = hist[i];
}

__global__ __launch_bounds__(256) void bucket_totals(const int* __restrict__ counts,
                                                     int* __restrict__ tot) {
    __shared__ int red[256];
    int b = blockIdx.x, t = threadIdx.x;
    int s = 0;
    for (int blk = t; blk < NCHUNK; blk += 256) s += counts[blk * N_BUCKETS + b];
    red[t] = s;
    __syncthreads();
    for (int o = 128; o > 0; o >>= 1) {
        if (t < o) red[t] += red[t + o];
        __syncthreads();
    }
    if (t == 0) tot[b] = red[0];
}

__global__ __launch_bounds__(1024) void scan_buckets(const int* __restrict__ tot,
                                                     int* __restrict__ base, int nb) {
    __shared__ int lds[1024];
    int t = threadIdx.x;
    int v = (t < nb) ? tot[t] : 0;
    lds[t] = v;
    __syncthreads();
    for (int off = 1; off < 1024; off <<= 1) {
        int a = (t >= off) ? lds[t - off] : 0;
        __syncthreads();
        lds[t] += a;
        __syncthreads();
    }
    int excl = lds[t] - v;
    if (t < nb) base[t] = excl;
    if (t == nb) base[t] = excl;
}

__global__ __launch_bounds__(512) void column_scan(const int* __restrict__ counts,
                                                   const int* __restrict__ base,
                                                   int* __restrict__ offs) {
    __shared__ int lds[512];
    int b = blockIdx.x, t = threadIdx.x;
    int v = (t < NCHUNK) ? counts[t * N_BUCKETS + b] : 0;
    lds[t] = v;
    __syncthreads();
    for (int off = 1; off < 512; off <<= 1) {
        int a = (t >= off) ? lds[t - off] : 0;
        __syncthreads();
        lds[t] += a;
        __syncthreads();
    }
    if (t < NCHUNK) offs[t * N_BUCKETS + b] = base[b] + lds[t] - v;
}

__global__ __launch_bounds__(256) void block_scatter(const int* __restrict__ src,
                                                     const int* __restrict__ dst,
                                                     const int* __restrict__ offs,
                                                     unsigned int* __restrict__ rec, int nE) {
    __shared__ int cur[N_BUCKETS];
    int blk = blockIdx.x, t = threadIdx.x;
    for (int i = t; i < N_BUCKETS; i += 256) cur[i] = offs[blk * N_BUCKETS + i];
    __syncthreads();
    int lo = blk * CHUNK;
    int hi = lo + CHUNK < nE ? lo + CHUNK : nE;
    for (int i = lo + t; i < hi; i += 256) {
        int d = dst[i];
        int b = d >> BUCKET_BITS;
        int pos = atomicAdd(&cur[b], 1);  // LDS atomic
        rec[pos] = (unsigned int)src[i] | ((unsigned int)(d & (NPB - 1)) << 17);
    }
}

__global__ __launch_bounds__(512) void bucket_csr(const unsigned int* __restrict__ rec,
                                                  const int* __restrict__ base,
                                                  int* __restrict__ ptr, float* __restrict__ dinv,
                                                  int* __restrict__ csr_src, int n) {
    __shared__ int hist[NPB];
    __shared__ int sc[NPB];
    __shared__ int cur[NPB];
    int b = blockIdx.x;
    int lo = base[b], hi = base[b + 1];
    int t = threadIdx.x;
    if (t < NPB) hist[t] = 0;
    __syncthreads();
    for (int i = lo + t; i < hi; i += 512) atomicAdd(&hist[rec[i] >> 17], 1);
    __syncthreads();
    if (t < NPB) sc[t] = hist[t];
    __syncthreads();
    for (int off = 1; off < NPB; off <<= 1) {
        int a = (t < NPB && t >= off) ? sc[t - off] : 0;
        __syncthreads();
        if (t < NPB) sc[t] += a;
        __syncthreads();
    }
    if (t < NPB) {
        int node = b * NPB + t;
        int incl = sc[t];
        int excl = incl - hist[t];
        if (node < n) {
            ptr[node] = lo + incl;
            dinv[node] = rsqrtf((float)hist[t] + 1.0f);
        }
        cur[t] = lo + excl;
    }
    __syncthreads();
    for (int i = lo + t; i < hi; i += 512) {
        unsigned int r = rec[i];
        int pos = atomicAdd(&cur[r >> 17], 1);
        csr_src[pos] = (int)(r & 0x1FFFFu);
    }
}

// ---------------- x -> fp8 pre-scaled: x_pre[n] = fp8(dinv[n] * x[n]) ----------------
__global__ void convert_x_pre(const float* __restrict__ x, const float* __restrict__ dinv,
                              unsigned int* __restrict__ xp, int n) {
    int tid = blockIdx.x * blockDim.x + threadIdx.x;  // over n*F_IN/4
    if (tid >= n * (F_IN / 4)) return;
    int node = tid / (F_IN / 4);
    float di = dinv[node];
    float4 v = ((const float4*)x)[tid];
    xp[tid] = pack4_fp8(v.x * di, v.y * di, v.z * di, v.w * di);
}

// ---------------- pack W[K][256] fp32 -> hi/lo bf16 in MFMA B-fragment order ----------------
__global__ void pack_w(const float* __restrict__ W, unsigned short* __restrict__ hi,
                       unsigned short* __restrict__ lo, int K) {
    int idx = blockIdx.x * blockDim.x + threadIdx.x;
    if (idx >= K * HDIM) return;
    int k = idx >> 8, c = idx & 255;
    float w = W[idx];
    unsigned short h = f2bf(w);
    float hf = __uint_as_float((unsigned int)h << 16);
    unsigned short l = f2bf(w - hf);
    int pos = ((k >> 5) * 16 + (c >> 4)) * 512 + ((((k >> 3) & 3) * 16) + (c & 15)) * 8 + (k & 7);
    hi[pos] = h;
    lo[pos] = l;
}

// ---------------- aggregation (fp8 in, bf16 out), 8-deep load pipeline ----------------
__global__ void csr_agg128_fp8(const unsigned char* __restrict__ h, const int* __restrict__ ptr,
                               const int* __restrict__ csr, const float* __restrict__ dinv,
                               unsigned short* __restrict__ out, int n) {
    int wave = threadIdx.x >> 6, lane = threadIdx.x & 63;
    int node = blockIdx.x * 4 + wave;
    if (node >= n) return;
    int begin = node ? ptr[node - 1] : 0;
    int end = ptr[node];
    unsigned int u = *(const unsigned short*)(h + (size_t)node * 128 + lane * 2);
    f32x2 v = __builtin_amdgcn_cvt_pk_f32_fp8((int)u, false);
    float a0 = v.x, a1 = v.y;
    int i = begin;
    for (; i + 8 <= end; i += 8) {
        unsigned int uu[8];
#pragma unroll
        for (int j = 0; j < 8; j++) {
            int s = csr[i + j];
            uu[j] = *(const unsigned short*)(h + (size_t)s * 128 + lane * 2);
        }
#pragma unroll
        for (int j = 0; j < 8; j++) {
            f32x2 d = __builtin_amdgcn_cvt_pk_f32_fp8((int)uu[j], false);
            a0 += d.x; a1 += d.y;
        }
    }
    for (; i < end; i++) {
        int s = csr[i];
        unsigned int u0 = *(const unsigned short*)(h + (size_t)s * 128 + lane * 2);
        f32x2 d = __builtin_amdgcn_cvt_pk_f32_fp8((int)u0, false);
        a0 += d.x; a1 += d.y;
    }
    float dn = dinv[node];
    unsigned int o = (unsigned int)f2bf(a0 * dn) | ((unsigned int)f2bf(a1 * dn) << 16);
    *(unsigned int*)(out + (size_t)node * 128 + lane * 2) = o;
}

__global__ void csr_agg256_fp8(const unsigned char* __restrict__ h, const int* __restrict__ ptr,
                               const int* __restrict__ csr, const float* __restrict__ dinv,
                               unsigned short* __restrict__ out, int n) {
    int wave = threadIdx.x >> 6, lane = threadIdx.x & 63;
    int node = blockIdx.x * 4 + wave;
    if (node >= n) return;
    int begin = node ? ptr[node - 1] : 0;
    int end = ptr[node];
    unsigned int u = *(const unsigned int*)(h + (size_t)node * 256 + lane * 4);
    f32x2 vl = __builtin_amdgcn_cvt_pk_f32_fp8((int)u, false);
    f32x2 vh = __builtin_amdgcn_cvt_pk_f32_fp8((int)u, true);
    float a0 = vl.x, a1 = vl.y, a2 = vh.x, a3 = vh.y;
    int i = begin;
    for (; i + 8 <= end; i += 8) {
        unsigned int uu[8];
#pragma unroll
        for (int j = 0; j < 8; j++) {
            int s = csr[i + j];
            uu[j] = *(const unsigned int*)(h + (size_t)s * 256 + lane * 4);
        }
#pragma unroll
        for (int j = 0; j < 8; j++) {
            f32x2 dl = __builtin_amdgcn_cvt_pk_f32_fp8((int)uu[j], false);
            f32x2 dh = __builtin_amdgcn_cvt_pk_f32_fp8((int)uu[j], true);
            a0 += dl.x; a1 += dl.y; a2 += dh.x; a3 += dh.y;
        }
    }
    for (; i < end; i++) {
        int s = csr[i];
        unsigned int u0 = *(const unsigned int*)(h + (size_t)s * 256 + lane * 4);
        f32x2 dl = __builtin_amdgcn_cvt_pk_f32_fp8((int)u0, false);
        f32x2 dh = __builtin_amdgcn_cvt_pk_f32_fp8((int)u0, true);
        a0 += dl.x; a1 += dl.y; a2 += dh.x; a3 += dh.y;
    }
    float dn = dinv[node];
    uint2 o;
    o.x = (unsigned int)f2bf(a0 * dn) | ((unsigned int)f2bf(a1 * dn) << 16);
    o.y = (unsigned int)f2bf(a2 * dn) | ((unsigned int)f2bf(a3 * dn) << 16);
    *(uint2*)(out + (size_t)node * 256 + lane * 4) = o;
}

// ---------------- MFMA GEMM: out[n,256] = act(A[n,K] @ (Whi+Wlo) + b) ----------------
// block: 4 waves = 64 rows x 256 cols; wave: 32 rows (2 strips) x 128 cols (8 ct)
// PRESCALE: out fp8 = fp8(dinv[row]*relu(v));  else: out fp32 = relu(v)
template <int K, bool PRESCALE>
__global__ __launch_bounds__(256, 3) void gemm_mfma(
    const unsigned short* __restrict__ A, const unsigned short* __restrict__ Whi,
    const unsigned short* __restrict__ Wlo, const float* __restrict__ bias,
    const float* __restrict__ dinv, void* __restrict__ outp, int n) {
    int wave = threadIdx.x >> 6, lane = threadIdx.x & 63;
    int quad = lane >> 4, l16 = lane & 15;
    int rowgrp = wave >> 1, colhalf = wave & 1;
    int rowbase = blockIdx.x * 64 + rowgrp * 32;

    f32x4 acc[2][8];
#pragma unroll
    for (int s = 0; s < 2; s++)
#pragma unroll
        for (int ct = 0; ct < 8; ct++) acc[s][ct] = (f32x4){0.f, 0.f, 0.f, 0.f};

    int r0 = rowbase + l16;
    int r1 = rowbase + 16 + l16;
    int rc0 = r0 < n ? r0 : n - 1;
    int rc1 = r1 < n ? r1 : n - 1;

    for (int kt = 0; kt < K / 32; kt++) {
        bf16x8 a0 = *(const bf16x8*)(A + (size_t)rc0 * K + kt * 32 + quad * 8);
        bf16x8 a1 = *(const bf16x8*)(A + (size_t)rc1 * K + kt * 32 + quad * 8);
        const unsigned short* wh = Whi + ((size_t)kt * 16 + colhalf * 8) * 512 + lane * 8;
        const unsigned short* wl = Wlo + ((size_t)kt * 16 + colhalf * 8) * 512 + lane * 8;
#pragma unroll
        for (int ct = 0; ct < 8; ct++) {
            bf16x8 bh = *(const bf16x8*)(wh + ct * 512);
            bf16x8 bl = *(const bf16x8*)(wl + ct * 512);
            acc[0][ct] = __builtin_amdgcn_mfma_f32_16x16x32_bf16(a0, bh, acc[0][ct], 0, 0, 0);
            acc[0][ct] = __builtin_amdgcn_mfma_f32_16x16x32_bf16(a0, bl, acc[0][ct], 0, 0, 0);
            acc[1][ct] = __builtin_amdgcn_mfma_f32_16x16x32_bf16(a1, bh, acc[1][ct], 0, 0, 0);
            acc[1][ct] = __builtin_amdgcn_mfma_f32_16x16x32_bf16(a1, bl, acc[1][ct], 0, 0, 0);
        }
    }

#pragma unroll
    for (int s = 0; s < 2; s++) {
#pragma unroll
        for (int ct = 0; ct < 8; ct++) {
            int col = colhalf * 128 + ct * 16 + l16;
            float b = bias[col];
#pragma unroll
            for (int r = 0; r < 4; r++) {
                int row = rowbase + s * 16 + quad * 4 + r;
                if (row < n) {
                    float v = acc[s][ct][r] + b;
                    v = v > 0.0f ? v : 0.0f;
                    if (PRESCALE) {
                        ((unsigned char*)outp)[(size_t)row * HDIM + col] = pack1_fp8(v * dinv[row]);
                    } else {
                        ((float*)outp)[(size_t)row * HDIM + col] = v;
                    }
                }
            }
        }
    }
}

// ---------------- pooling (batch sorted -> run-length) ----------------
__global__ void pool_sum_runs(const float* __restrict__ h, const int* __restrict__ batch,
                              float* __restrict__ pool, float* __restrict__ cnt, int n) {
    constexpr int ROWS = 128;
    int f = threadIdx.x;
    int r0 = blockIdx.x * ROWS;
    int rend = r0 + ROWS;
    if (rend > n) rend = n;
    float acc = 0.0f;
    int cur = batch[r0];
    int runlen = 0;
    for (int r = r0; r < rend; r++) {
        int g = batch[r];
        if (g != cur) {
            atomicAdd(&pool[cur * HDIM + f], acc);
            if (f == 0) atomicAdd(&cnt[cur], (float)runlen);
            acc = 0.0f; runlen = 0; cur = g;
        }
        acc += h[(size_t)r * HDIM + f];
        runlen++;
    }
    atomicAdd(&pool[cur * HDIM + f], acc);
    if (f == 0) atomicAdd(&cnt[cur], (float)runlen);
}

__global__ void final_head(const float* __restrict__ pool, const float* __restrict__ cnt,
                           const float* __restrict__ fcw, const float* __restrict__ fcb,
                           float* __restrict__ out) {
    int g = threadIdx.x;
    if (g < N_GRAPHS) {
        float c = cnt[g];
        c = c > 1.0f ? c : 1.0f;
        float inv = 1.0f / c;
        float l0 = fcb[0], l1 = fcb[1];
        for (int f = 0; f < HDIM; f++) {
            float p = pool[g * HDIM + f] * inv;
            l0 += p * fcw[f * 2 + 0];
            l1 += p * fcw[f * 2 + 1];
        }
        float m = fmaxf(l0, l1);
        float lse = m + logf(expf(l0 - m) + expf(l1 - m));
        out[g * 2 + 0] = l0 - lse;
        out[g * 2 + 1] = l1 - lse;
    }
}

extern "C" void kernel_launch(void* const* d_in, const int* in_sizes, int n_in,
                              void* d_out, int out_size, void* d_ws, size_t ws_size,
                              hipStream_t stream) {
    const float* x = (const float*)d_in[0];
    const int* ei = (const int*)d_in[1];
    const int* batch = (const int*)d_in[2];
    const float* W1 = (const float*)d_in[3];
    const float* b1 = (const float*)d_in[4];
    const float* W2 = (const float*)d_in[5];
    const float* b2 = (const float*)d_in[6];
    const float* fcw = (const float*)d_in[7];
    const float* fcb = (const float*)d_in[8];
    float* out = (float*)d_out;

    const int* src = ei;
    const int* dst = ei + N_EDGES;

    // ---- workspace layout (bytes) ----
    char* ws = (char*)d_ws;
    float* dinv = (float*)ws;            ws += 4 * ((N_NODES + 255) & ~255);
    int* ptr = (int*)ws;                 ws += 4 * ((N_NODES + 255) & ~255);
    int* csr_src = (int*)ws;             ws += 4 * (size_t)N_EDGES;
    int* counts = (int*)ws;              ws += 4 * (size_t)NCHUNK * N_BUCKETS;
    int* offs = (int*)ws;                ws += 4 * (size_t)NCHUNK * N_BUCKETS;
    int* tot = (int*)ws;                 ws += 4 * 1024;
    int* bbase = (int*)ws;               ws += 4 * 1024;
    unsigned short* W1hi = (unsigned short*)ws; ws += 2 * F_IN * HDIM;
    unsigned short* W1lo = (unsigned short*)ws; ws += 2 * F_IN * HDIM;
    unsigned short* W2hi = (unsigned short*)ws; ws += 2 * HDIM * HDIM;
    unsigned short* W2lo = (unsigned short*)ws; ws += 2 * HDIM * HDIM;
    float* pool = (float*)ws;            ws += 4 * N_GRAPHS * HDIM;
    float* cnt = (float*)ws;             ws += 4 * ((N_GRAPHS + 63) & ~63);
    // R0 region (N*HDIM*4 = 102.4MB): x_pre fp8 | A1 bf16 | h1_pre fp8; reused as h2 fp32
    char* R0 = ws;                       ws += 4 * (size_t)N_NODES * HDIM;
    unsigned char* x_pre = (unsigned char*)R0;                                 // N*128 fp8
    unsigned short* A1 = (unsigned short*)(R0 + (size_t)N_NODES * F_IN);       // N*128 bf16
    unsigned char* h1_pre = (unsigned char*)(R0 + 3 * (size_t)N_NODES * F_IN); // N*256 fp8
    float* h2 = (float*)R0;                                                    // N*256 fp32
    unsigned short* A2 = (unsigned short*)ws;  // N*256 bf16 (layer 2 only)
    // records overlay A2 (dead until layer 2): N_EDGES*4 = 12.8MB <= 51.2MB
    unsigned int* records = (unsigned int*)A2;

    // ---- atomic-free bucketed CSR build + dinv ----
    block_count<<<NCHUNK, 256, 0, stream>>>(dst, counts, N_EDGES);
    bucket_totals<<<N_BUCKETS, 256, 0, stream>>>(counts, tot);
    scan_buckets<<<1, 1024, 0, stream>>>(tot, bbase, N_BUCKETS);
    column_scan<<<N_BUCKETS, 512, 0, stream>>>(counts, bbase, offs);
    block_scatter<<<NCHUNK, 256, 0, stream>>>(src, dst, offs, records, N_EDGES);
    bucket_csr<<<N_BUCKETS, 512, 0, stream>>>(records, bbase, ptr, dinv, csr_src, N_NODES);

    // ---- conversions / weight packing ----
    convert_x_pre<<<(N_NODES * (F_IN / 4) + 255) / 256, 256, 0, stream>>>(
        x, dinv, (unsigned int*)x_pre, N_NODES);
    pack_w<<<(F_IN * HDIM + 255) / 256, 256, 0, stream>>>(W1, W1hi, W1lo, F_IN);
    pack_w<<<(HDIM * HDIM + 255) / 256, 256, 0, stream>>>(W2, W2hi, W2lo, HDIM);

    // ---- layer 1 ----
    csr_agg128_fp8<<<(N_NODES + 3) / 4, 256, 0, stream>>>(x_pre, ptr, csr_src, dinv, A1, N_NODES);
    gemm_mfma<F_IN, true><<<(N_NODES + 63) / 64, 256, 0, stream>>>(A1, W1hi, W1lo, b1, dinv,
                                                                   h1_pre, N_NODES);
    // ---- layer 2 ----
    csr_agg256_fp8<<<(N_NODES + 3) / 4, 256, 0, stream>>>(h1_pre, ptr, csr_src, dinv, A2, N_NODES);
    gemm_mfma<HDIM, false><<<(N_NODES + 63) / 64, 256, 0, stream>>>(A2, W2hi, W2lo, b2, dinv,
                                                                    h2, N_NODES);

    // ---- pool + head ----
    zero_f<<<(N_GRAPHS * HDIM + N_GRAPHS + 255) / 256, 256, 0, stream>>>(
        pool, N_GRAPHS * HDIM + N_GRAPHS);
    pool_sum_runs<<<(N_NODES + 127) / 128, 256, 0, stream>>>(h2, batch, pool, cnt, N_NODES);
    final_head<<<1, 64, 0, stream>>>(pool, cnt, fcw, fcb, out);
}